// Round 4
// baseline (20322.441 us; speedup 1.0000x reference)
//
#include <hip/hip_runtime.h>
#include <hip/hip_bf16.h>
#include <hip/hip_cooperative_groups.h>

namespace cg = cooperative_groups;

// Problem dims (fixed)
#define B_ 64
#define T_ 512
#define D_ 1024
#define NQ_ (B_*T_*D_)      // 33554432
#define NI_ (B_*T_)         // 32768

typedef __attribute__((ext_vector_type(8))) short bf16x8;
typedef __attribute__((ext_vector_type(4))) float f32x4;

__device__ inline ushort f2bf(float f) {
    uint x = __float_as_uint(f);
    return (ushort)((x + 0x7FFFu + ((x >> 16) & 1u)) >> 16);
}
__device__ inline float bf2f(ushort u) { return __uint_as_float(((uint)u) << 16); }

// ---------------- fp32 -> bf16 weight conversion ----------------
__global__ __launch_bounds__(256) void conv_kernel(const float* __restrict__ src,
                                                   ushort* __restrict__ dst, int n) {
    int i = (blockIdx.x * 256 + threadIdx.x) * 4;
    if (i >= n) return;
    float4 v = *reinterpret_cast<const float4*>(src + i);
    ushort4 o;
    o.x = f2bf(v.x); o.y = f2bf(v.y); o.z = f2bf(v.z); o.w = f2bf(v.w);
    *reinterpret_cast<ushort4*>(dst + i) = o;
}

// ---- numpy-faithful fp32 pairwise sum of squares, n=1024 (8 leaves of 128) ----
__device__ inline float np_pairwise_sq_1024(const float* a) {
    float L[8];
    for (int c = 0; c < 8; ++c) {
        const float* p = a + c * 128;
        float r[8];
        #pragma unroll
        for (int k = 0; k < 8; ++k) r[k] = __fmul_rn(p[k], p[k]);
        for (int i = 8; i < 128; i += 8) {
            #pragma unroll
            for (int k = 0; k < 8; ++k) {
                float v = p[i + k];
                r[k] = __fadd_rn(r[k], __fmul_rn(v, v));
            }
        }
        L[c] = __fadd_rn(__fadd_rn(__fadd_rn(r[0], r[1]), __fadd_rn(r[2], r[3])),
                         __fadd_rn(__fadd_rn(r[4], r[5]), __fadd_rn(r[6], r[7])));
    }
    return __fadd_rn(__fadd_rn(__fadd_rn(L[0], L[1]), __fadd_rn(L[2], L[3])),
                     __fadd_rn(__fadd_rn(L[4], L[5]), __fadd_rn(L[6], L[7])));
}

// ---------------- codebook norms (fp32, numpy pairwise) ----------------
__global__ __launch_bounds__(256) void c2_kernel(const float* __restrict__ cb,
                                                 float* __restrict__ c2) {
    int j = threadIdx.x;
    c2[j] = np_pairwise_sq_1024(cb + (size_t)j * D_);
}

// ---------------- quantize: fp32-faithful argmin, 8 rows/block ----------------
__global__ __launch_bounds__(256) void quantize_kernel(const float* __restrict__ Z,
                                                       const float* __restrict__ cb,
                                                       const float* __restrict__ c2,
                                                       float* __restrict__ qout,
                                                       float* __restrict__ idxout,
                                                       int* __restrict__ idxi) {
    __shared__ float rows[8][D_];      // 32 KB
    __shared__ float z2s[8];
    __shared__ float d2s[256];
    __shared__ int   idxs[256];
    __shared__ int   bestIdx[8];
    int tid = threadIdx.x;
    size_t row0 = (size_t)blockIdx.x * 8;

    for (int p = 0; p < 8; ++p) {
        float4 v = *reinterpret_cast<const float4*>(Z + (row0 + p) * D_ + tid * 4);
        *reinterpret_cast<float4*>(&rows[p][tid * 4]) = v;
    }
    __syncthreads();

    if (tid < 8) z2s[tid] = np_pairwise_sq_1024(rows[tid]);

    float g2[8];
    #pragma unroll
    for (int r = 0; r < 8; ++r) g2[r] = 0.0f;
    const float* crow = cb + (size_t)tid * D_;
    for (int e = 0; e < D_; e += 4) {
        float4 cv = *reinterpret_cast<const float4*>(crow + e);
        #pragma unroll
        for (int r = 0; r < 8; ++r) {
            g2[r] = __fmaf_rn(__fmul_rn(2.0f, rows[r][e]),     cv.x, g2[r]);
            g2[r] = __fmaf_rn(__fmul_rn(2.0f, rows[r][e + 1]), cv.y, g2[r]);
            g2[r] = __fmaf_rn(__fmul_rn(2.0f, rows[r][e + 2]), cv.z, g2[r]);
            g2[r] = __fmaf_rn(__fmul_rn(2.0f, rows[r][e + 3]), cv.w, g2[r]);
        }
    }
    __syncthreads();

    for (int r = 0; r < 8; ++r) {
        d2s[tid] = __fadd_rn(__fsub_rn(z2s[r], g2[r]), c2[tid]);
        idxs[tid] = tid;
        __syncthreads();
        for (int s = 128; s > 0; s >>= 1) {
            if (tid < s) {
                float ov = d2s[tid + s]; int oi = idxs[tid + s];
                if (ov < d2s[tid] || (ov == d2s[tid] && oi < idxs[tid])) {
                    d2s[tid] = ov; idxs[tid] = oi;
                }
            }
            __syncthreads();
        }
        if (tid == 0) bestIdx[r] = idxs[0];
        __syncthreads();
    }

    if (tid < 8) {
        idxout[row0 + tid] = (float)bestIdx[tid];
        idxi[row0 + tid]   = bestIdx[tid];
    }
    for (int r = 0; r < 8; ++r) {
        int bi = bestIdx[r];
        float4 v = *reinterpret_cast<const float4*>(cb + (size_t)bi * D_ + tid * 4);
        *reinterpret_cast<float4*>(qout + (row0 + r) * D_ + tid * 4) = v;
    }
}

// ---------------- G = cb @ Wih^T  (256 x 3072, fp32 out, bf16 MFMA) ----------------
__global__ __launch_bounds__(256) void gmat_kernel(const float* __restrict__ cb,
                                                   const float* __restrict__ Wih,
                                                   float* __restrict__ G) {
    int m0 = blockIdx.x * 64;
    int n0 = blockIdx.y * 64;
    __shared__ ushort As[64][136];
    __shared__ ushort Bs[64][136];
    int tid = threadIdx.x;
    int w = tid >> 6, l = tid & 63, lr = l & 15, lk = l >> 4;
    f32x4 acc[4];
    #pragma unroll
    for (int i = 0; i < 4; ++i) acc[i] = f32x4{0.f, 0.f, 0.f, 0.f};

    for (int kc = 0; kc < D_; kc += 128) {
        for (int v = tid; v < 2048; v += 256) {
            int r = (v >> 4) & 63, kp = (v & 15) << 3;
            const float* src = (v < 1024) ? (cb  + (size_t)(m0 + r) * D_ + kc + kp)
                                          : (Wih + (size_t)(n0 + r) * D_ + kc + kp);
            float4 f0 = *reinterpret_cast<const float4*>(src);
            float4 f1 = *reinterpret_cast<const float4*>(src + 4);
            uint4 pk;
            pk.x = (uint)f2bf(f0.x) | ((uint)f2bf(f0.y) << 16);
            pk.y = (uint)f2bf(f0.z) | ((uint)f2bf(f0.w) << 16);
            pk.z = (uint)f2bf(f1.x) | ((uint)f2bf(f1.y) << 16);
            pk.w = (uint)f2bf(f1.z) | ((uint)f2bf(f1.w) << 16);
            ushort* dst = (v < 1024) ? &As[r][kp] : &Bs[r][kp];
            *reinterpret_cast<uint4*>(dst) = pk;
        }
        __syncthreads();
        #pragma unroll
        for (int kk = 0; kk < 4; ++kk) {
            bf16x8 bb = *reinterpret_cast<const bf16x8*>(&Bs[(w << 4) + lr][(kk << 5) + (lk << 3)]);
            #pragma unroll
            for (int mi = 0; mi < 4; ++mi) {
                bf16x8 a = *reinterpret_cast<const bf16x8*>(&As[(mi << 4) + lr][(kk << 5) + (lk << 3)]);
                acc[mi] = __builtin_amdgcn_mfma_f32_16x16x32_bf16(a, bb, acc[mi], 0, 0, 0);
            }
        }
        __syncthreads();
    }
    int n = n0 + (w << 4) + lr;
    #pragma unroll
    for (int mi = 0; mi < 4; ++mi)
        #pragma unroll
        for (int reg = 0; reg < 4; ++reg)
            G[(size_t)(m0 + (mi << 4) + (lk << 2) + reg) * 3072 + n] = acc[mi][reg];
}

// ---------------- persistent cooperative recurrence + inline proj/CPC ----------------
__global__ __launch_bounds__(256) void recur_kernel(
    const ushort* __restrict__ Whh_bf,
    const float*  __restrict__ G,
    const int*    __restrict__ idx_i,
    const float*  __restrict__ bih,
    const float*  __restrict__ bhh,
    const ushort* __restrict__ projW_bf,
    const float*  __restrict__ projb,
    const float*  __restrict__ Z,
    ushort* __restrict__ hbuf,    // 2 x (64*1024)
    ushort* __restrict__ ring,    // RING x (64*1024)
    ushort* __restrict__ hproj,   // RING x (64*1024)
    double* __restrict__ accum,
    int RING_)
{
    cg::grid_group gg = cg::this_grid();
    __shared__ ushort HsS[2][64][136];   // 34816 B
    __shared__ ushort WsS[2][48][136];   // 26112 B
    __shared__ double red[256];          //  2048 B

    const int blk = blockIdx.x;          // 0..63
    const int tid = threadIdx.x;
    const int w = tid >> 6, l = tid & 63;
    const int lr = l & 15, lk = l >> 4;
    const int j0 = blk << 4;
    const int j  = j0 + lr;
    const int b_base = (w << 4) + (lk << 2);

    const float bihr = bih[j], bihz = bih[1024 + j], bihn = bih[2048 + j];
    const float bhhr = bhh[j], bhhz = bhh[1024 + j], bhhn = bhh[2048 + j];
    float hfp[4] = {0.f, 0.f, 0.f, 0.f};

    for (int t = 0; t < T_; ++t) {
        const ushort* hin  = hbuf + (size_t)(t & 1) * 65536;
        ushort*       hout = hbuf + (size_t)((t + 1) & 1) * 65536;
        int slot = t & (RING_ - 1);

        f32x4 acc[3];
        acc[0] = f32x4{0.f,0.f,0.f,0.f};
        acc[1] = f32x4{0.f,0.f,0.f,0.f};
        acc[2] = f32x4{0.f,0.f,0.f,0.f};

        uint4 pf[7];
        // prologue: load + commit k-chunk 0 (1792 uint4 = 7 per thread)
        #pragma unroll
        for (int i = 0; i < 7; ++i) {
            int v = tid + (i << 8);
            if (v < 1024) {
                int r = v >> 4, kp = (v & 15) << 3;
                pf[i] = *reinterpret_cast<const uint4*>(hin + ((size_t)r << 10) + kp);
            } else {
                int r = (v - 1024) >> 4, kp = (v & 15) << 3;
                int grow = ((r >> 4) << 10) + j0 + (r & 15);
                pf[i] = *reinterpret_cast<const uint4*>(Whh_bf + ((size_t)grow << 10) + kp);
            }
        }
        #pragma unroll
        for (int i = 0; i < 7; ++i) {
            int v = tid + (i << 8);
            if (v < 1024) {
                int r = v >> 4, kp = (v & 15) << 3;
                *reinterpret_cast<uint4*>(&HsS[0][r][kp]) = pf[i];
            } else {
                int r = (v - 1024) >> 4, kp = (v & 15) << 3;
                *reinterpret_cast<uint4*>(&WsS[0][r][kp]) = pf[i];
            }
        }
        for (int kcb = 0; kcb < 8; ++kcb) {
            int kcn = (kcb + 1) << 7;
            if (kcb < 7) {
                #pragma unroll
                for (int i = 0; i < 7; ++i) {
                    int v = tid + (i << 8);
                    if (v < 1024) {
                        int r = v >> 4, kp = (v & 15) << 3;
                        pf[i] = *reinterpret_cast<const uint4*>(hin + ((size_t)r << 10) + kcn + kp);
                    } else {
                        int r = (v - 1024) >> 4, kp = (v & 15) << 3;
                        int grow = ((r >> 4) << 10) + j0 + (r & 15);
                        pf[i] = *reinterpret_cast<const uint4*>(Whh_bf + ((size_t)grow << 10) + kcn + kp);
                    }
                }
            }
            __syncthreads();
            int bq = kcb & 1;
            #pragma unroll
            for (int kk = 0; kk < 4; ++kk) {
                bf16x8 a = *reinterpret_cast<const bf16x8*>(&HsS[bq][(w << 4) + lr][(kk << 5) + (lk << 3)]);
                #pragma unroll
                for (int g = 0; g < 3; ++g) {
                    bf16x8 bb = *reinterpret_cast<const bf16x8*>(&WsS[bq][(g << 4) + lr][(kk << 5) + (lk << 3)]);
                    acc[g] = __builtin_amdgcn_mfma_f32_16x16x32_bf16(a, bb, acc[g], 0, 0, 0);
                }
            }
            if (kcb < 7) {
                int bn = (kcb + 1) & 1;
                #pragma unroll
                for (int i = 0; i < 7; ++i) {
                    int v = tid + (i << 8);
                    if (v < 1024) {
                        int r = v >> 4, kp = (v & 15) << 3;
                        *reinterpret_cast<uint4*>(&HsS[bn][r][kp]) = pf[i];
                    } else {
                        int r = (v - 1024) >> 4, kp = (v & 15) << 3;
                        *reinterpret_cast<uint4*>(&WsS[bn][r][kp]) = pf[i];
                    }
                }
            }
        }

        // gates + h update (h carried in registers)
        #pragma unroll
        for (int reg = 0; reg < 4; ++reg) {
            int b = b_base + reg;
            int ci = idx_i[(b << 9) + t];
            const float* Gr = G + (size_t)ci * 3072 + j;
            float gir = Gr[0], giz = Gr[1024], gin = Gr[2048];
            float rr = 1.0f / (1.0f + expf(-(gir + bihr + acc[0][reg] + bhhr)));
            float zz = 1.0f / (1.0f + expf(-(giz + bihz + acc[1][reg] + bhhz)));
            float nn = tanhf(gin + bihn + rr * (acc[2][reg] + bhhn));
            float hn = (1.0f - zz) * nn + zz * hfp[reg];
            hfp[reg] = hn;
            ushort hb = f2bf(hn);
            hout[(b << 10) + j] = hb;
            ring[((size_t)slot << 16) + (b << 10) + j] = hb;
        }
        gg.sync();

        if (((t + 1) & (RING_ - 1)) == 0) {
            int t0 = t + 1 - RING_;
            // ---- proj: units = RING*16 (t' x 64-col n-group) ----
            for (int u = blk; u < (RING_ << 4); u += 64) {
                int sl = u >> 4;
                int n0 = (u & 15) << 6;
                f32x4 pacc[4];
                #pragma unroll
                for (int i = 0; i < 4; ++i) pacc[i] = f32x4{0.f,0.f,0.f,0.f};
                for (int kc = 0; kc < D_; kc += 128) {
                    for (int v = tid; v < 2048; v += 256) {
                        int r = (v >> 4) & 63, kp = (v & 15) << 3;
                        if (v < 1024)
                            *reinterpret_cast<uint4*>(&HsS[0][r][kp]) =
                                *reinterpret_cast<const uint4*>(ring + ((size_t)sl << 16) + ((size_t)r << 10) + kc + kp);
                        else
                            *reinterpret_cast<uint4*>(&HsS[1][r][kp]) =
                                *reinterpret_cast<const uint4*>(projW_bf + ((size_t)(n0 + r) << 10) + kc + kp);
                    }
                    __syncthreads();
                    #pragma unroll
                    for (int kk = 0; kk < 4; ++kk) {
                        bf16x8 bb = *reinterpret_cast<const bf16x8*>(&HsS[1][(w << 4) + lr][(kk << 5) + (lk << 3)]);
                        #pragma unroll
                        for (int mi = 0; mi < 4; ++mi) {
                            bf16x8 a = *reinterpret_cast<const bf16x8*>(&HsS[0][(mi << 4) + lr][(kk << 5) + (lk << 3)]);
                            pacc[mi] = __builtin_amdgcn_mfma_f32_16x16x32_bf16(a, bb, pacc[mi], 0, 0, 0);
                        }
                    }
                    __syncthreads();
                }
                int n = n0 + (w << 4) + lr;
                float pb = projb[n];
                #pragma unroll
                for (int mi = 0; mi < 4; ++mi)
                    #pragma unroll
                    for (int reg = 0; reg < 4; ++reg) {
                        int b = (mi << 4) + (lk << 2) + reg;
                        hproj[((size_t)sl << 16) + (b << 10) + n] = f2bf(pacc[mi][reg] + pb);
                    }
            }
            gg.sync();
            // ---- cpc: units = RING*3 (t' x k) ----
            for (int u = blk; u < RING_ * 3; u += 64) {
                int sl = u / 3;
                int kf = u - sl * 3 + 1;
                int tp = t0 + sl;
                if (tp >= T_ - kf) continue;
                f32x4 pacc[4];
                #pragma unroll
                for (int i = 0; i < 4; ++i) pacc[i] = f32x4{0.f,0.f,0.f,0.f};
                for (int kc = 0; kc < D_; kc += 128) {
                    for (int v = tid; v < 2048; v += 256) {
                        int r = (v >> 4) & 63, kp = (v & 15) << 3;
                        if (v < 1024) {
                            *reinterpret_cast<uint4*>(&HsS[0][r][kp]) =
                                *reinterpret_cast<const uint4*>(hproj + ((size_t)sl << 16) + ((size_t)r << 10) + kc + kp);
                        } else {
                            const float* zsrc = Z + ((((size_t)r << 9) + (tp + kf)) << 10) + kc + kp;
                            float4 f0 = *reinterpret_cast<const float4*>(zsrc);
                            float4 f1 = *reinterpret_cast<const float4*>(zsrc + 4);
                            uint4 pk;
                            pk.x = (uint)f2bf(f0.x) | ((uint)f2bf(f0.y) << 16);
                            pk.y = (uint)f2bf(f0.z) | ((uint)f2bf(f0.w) << 16);
                            pk.z = (uint)f2bf(f1.x) | ((uint)f2bf(f1.y) << 16);
                            pk.w = (uint)f2bf(f1.z) | ((uint)f2bf(f1.w) << 16);
                            *reinterpret_cast<uint4*>(&HsS[1][r][kp]) = pk;
                        }
                    }
                    __syncthreads();
                    #pragma unroll
                    for (int kk = 0; kk < 4; ++kk) {
                        bf16x8 bb = *reinterpret_cast<const bf16x8*>(&HsS[1][(w << 4) + lr][(kk << 5) + (lk << 3)]);
                        #pragma unroll
                        for (int mi = 0; mi < 4; ++mi) {
                            bf16x8 a = *reinterpret_cast<const bf16x8*>(&HsS[0][(mi << 4) + lr][(kk << 5) + (lk << 3)]);
                            pacc[mi] = __builtin_amdgcn_mfma_f32_16x16x32_bf16(a, bb, pacc[mi], 0, 0, 0);
                        }
                    }
                    __syncthreads();
                }
                double lsum = 0.0;
                int cc = (w << 4) + lr;
                #pragma unroll
                for (int mi = 0; mi < 4; ++mi)
                    #pragma unroll
                    for (int reg = 0; reg < 4; ++reg) {
                        int bb2 = (mi << 4) + (lk << 2) + reg;
                        double v = (double)pacc[mi][reg];
                        double s = 1.0 / (1.0 + exp(-v));
                        lsum += (0.1 / 4096.0) * (-log(1.0 - s + 1e-8));
                        if (bb2 == cc) lsum += (1.0 / 64.0) * (-log(s + 1e-8));
                    }
                red[tid] = lsum; __syncthreads();
                for (int s2 = 128; s2 > 0; s2 >>= 1) {
                    if (tid < s2) red[tid] += red[tid + s2];
                    __syncthreads();
                }
                if (tid == 0) atomicAdd(&accum[0], red[0]);
            }
            gg.sync();
        }
    }
}

// ---------------- VQ loss ----------------
__global__ __launch_bounds__(256) void vq_kernel(const float* __restrict__ Z,
                                                 const float* __restrict__ Q,
                                                 double* __restrict__ vq_sum) {
    size_t i0 = ((size_t)blockIdx.x * 256 + threadIdx.x) * 4;
    const size_t stride = (size_t)2048 * 256 * 4;
    double s = 0.0;
    for (size_t i = i0; i < (size_t)NQ_; i += stride) {
        float4 z = *reinterpret_cast<const float4*>(Z + i);
        float4 q = *reinterpret_cast<const float4*>(Q + i);
        double d0 = (double)z.x - (double)q.x;
        double d1 = (double)z.y - (double)q.y;
        double d2 = (double)z.z - (double)q.z;
        double d3 = (double)z.w - (double)q.w;
        s += d0*d0 + d1*d1 + d2*d2 + d3*d3;
    }
    __shared__ double red[256];
    int tid = threadIdx.x;
    red[tid] = s; __syncthreads();
    for (int k = 128; k > 0; k >>= 1) {
        if (tid < k) red[tid] += red[tid + k];
        __syncthreads();
    }
    if (tid == 0) atomicAdd(vq_sum, red[0]);
}

// ---------------- finalize scalars ----------------
__global__ void finalize_kernel(const double* __restrict__ accum,
                                float* __restrict__ scal) {
    double cp = accum[0] / 1527.0;
    double vq = accum[1] * 1.25 / (double)NQ_;
    scal[0] = (float)(cp + vq);
    scal[1] = (float)cp;
    scal[2] = (float)vq;
}

extern "C" void kernel_launch(void* const* d_in, const int* in_sizes, int n_in,
                              void* d_out, int out_size, void* d_ws, size_t ws_size,
                              hipStream_t stream) {
    const float* Z     = (const float*)d_in[0];
    const float* cb    = (const float*)d_in[1];
    const float* Wih   = (const float*)d_in[2];
    const float* Whh   = (const float*)d_in[3];
    const float* bih   = (const float*)d_in[4];
    const float* bhh   = (const float*)d_in[5];
    const float* projW = (const float*)d_in[6];
    const float* projb = (const float*)d_in[7];

    float* out       = (float*)d_out;
    float* quantized = out;
    float* idxout    = out + (size_t)NQ_;
    float* scal      = out + (size_t)NQ_ + NI_;

    char* p = (char*)d_ws;
    ushort* Whh_bf   = (ushort*)p;  p += 6291456;
    ushort* projW_bf = (ushort*)p;  p += 2097152;
    float*  G        = (float*)p;   p += 3145728;
    int*    idx_i    = (int*)p;     p += 131072;
    ushort* hbuf     = (ushort*)p;  p += 262144;
    float*  c2f      = (float*)p;   p += 4096;
    double* accum    = (double*)p;  p += 4096;
    size_t fixedsz = (size_t)(p - (char*)d_ws);

    int RINGv = 16;
    if (ws_size >= fixedsz + 2ull * 64 * 131072) RINGv = 64;
    else if (ws_size >= fixedsz + 2ull * 32 * 131072) RINGv = 32;
    ushort* ring  = (ushort*)p;  p += (size_t)RINGv * 131072;
    ushort* hproj = (ushort*)p;

    hipMemsetAsync(hbuf, 0, 262144, stream);
    hipMemsetAsync(accum, 0, 16, stream);

    conv_kernel<<<3072, 256, 0, stream>>>(Whh,   Whh_bf,   3145728);
    conv_kernel<<<1024, 256, 0, stream>>>(projW, projW_bf, 1048576);
    c2_kernel<<<1, 256, 0, stream>>>(cb, c2f);
    quantize_kernel<<<4096, 256, 0, stream>>>(Z, cb, c2f, quantized, idxout, idx_i);
    gmat_kernel<<<dim3(4, 48), 256, 0, stream>>>(cb, Wih, G);

    void* kargs[] = { (void*)&Whh_bf, (void*)&G, (void*)&idx_i,
                      (void*)&bih, (void*)&bhh,
                      (void*)&projW_bf, (void*)&projb, (void*)&Z,
                      (void*)&hbuf, (void*)&ring, (void*)&hproj,
                      (void*)&accum, (void*)&RINGv };
    hipLaunchCooperativeKernel((const void*)recur_kernel, dim3(64), dim3(256),
                               kargs, 0, stream);

    vq_kernel<<<2048, 256, 0, stream>>>(Z, quantized, &accum[1]);
    finalize_kernel<<<1, 1, 0, stream>>>(accum, scal);
}

// Round 5
// 13183.287 us; speedup vs baseline: 1.5415x; 1.5415x over previous
//
#include <hip/hip_runtime.h>
#include <hip/hip_bf16.h>

// Problem dims (fixed)
#define B_ 64
#define T_ 512
#define D_ 1024
#define NQ_ (B_*T_*D_)      // 33554432
#define NI_ (B_*T_)         // 32768

typedef __attribute__((ext_vector_type(8))) short bf16x8;
typedef __attribute__((ext_vector_type(4))) float f32x4;

__device__ inline ushort f2bf(float f) {
    uint x = __float_as_uint(f);
    return (ushort)((x + 0x7FFFu + ((x >> 16) & 1u)) >> 16);
}
__device__ inline float bf2f(ushort u) { return __uint_as_float(((uint)u) << 16); }

// agent-scope (device) coherent load/store: bypass stale per-XCD L2, compiler-tracked
__device__ __forceinline__ uint aload(const uint* p) {
    return __hip_atomic_load(p, __ATOMIC_RELAXED, __HIP_MEMORY_SCOPE_AGENT);
}
__device__ __forceinline__ void astore(ushort* p, ushort v) {
    __hip_atomic_store(p, v, __ATOMIC_RELAXED, __HIP_MEMORY_SCOPE_AGENT);
}

// fence-free grid barrier: monotonic counter at LLC (coherent across XCDs).
// __syncthreads drains each wave's write-through stores before tid0 arrives.
__device__ __forceinline__ void gbar(uint* bar, uint& tgt) {
    __syncthreads();
    tgt += 64;
    if (threadIdx.x == 0) {
        __hip_atomic_fetch_add(bar, 1u, __ATOMIC_RELAXED, __HIP_MEMORY_SCOPE_AGENT);
        while (__hip_atomic_load(bar, __ATOMIC_RELAXED, __HIP_MEMORY_SCOPE_AGENT) < tgt)
            __builtin_amdgcn_s_sleep(2);
    }
    __syncthreads();
}

// ---------------- fp32 -> bf16 weight conversion ----------------
__global__ __launch_bounds__(256) void conv_kernel(const float* __restrict__ src,
                                                   ushort* __restrict__ dst, int n) {
    int i = (blockIdx.x * 256 + threadIdx.x) * 4;
    if (i >= n) return;
    float4 v = *reinterpret_cast<const float4*>(src + i);
    ushort4 o;
    o.x = f2bf(v.x); o.y = f2bf(v.y); o.z = f2bf(v.z); o.w = f2bf(v.w);
    *reinterpret_cast<ushort4*>(dst + i) = o;
}

// ---- numpy-faithful fp32 pairwise sum of squares, n=1024 ----
__device__ inline float np_pairwise_sq_1024(const float* a) {
    float L[8];
    for (int c = 0; c < 8; ++c) {
        const float* p = a + c * 128;
        float r[8];
        #pragma unroll
        for (int k = 0; k < 8; ++k) r[k] = __fmul_rn(p[k], p[k]);
        for (int i = 8; i < 128; i += 8) {
            #pragma unroll
            for (int k = 0; k < 8; ++k) {
                float v = p[i + k];
                r[k] = __fadd_rn(r[k], __fmul_rn(v, v));
            }
        }
        L[c] = __fadd_rn(__fadd_rn(__fadd_rn(r[0], r[1]), __fadd_rn(r[2], r[3])),
                         __fadd_rn(__fadd_rn(r[4], r[5]), __fadd_rn(r[6], r[7])));
    }
    return __fadd_rn(__fadd_rn(__fadd_rn(L[0], L[1]), __fadd_rn(L[2], L[3])),
                     __fadd_rn(__fadd_rn(L[4], L[5]), __fadd_rn(L[6], L[7])));
}

// ---------------- codebook norms ----------------
__global__ __launch_bounds__(256) void c2_kernel(const float* __restrict__ cb,
                                                 float* __restrict__ c2) {
    int j = threadIdx.x;
    c2[j] = np_pairwise_sq_1024(cb + (size_t)j * D_);
}

// ---------------- quantize: fp32-faithful argmin, 8 rows/block ----------------
__global__ __launch_bounds__(256) void quantize_kernel(const float* __restrict__ Z,
                                                       const float* __restrict__ cb,
                                                       const float* __restrict__ c2,
                                                       float* __restrict__ qout,
                                                       float* __restrict__ idxout,
                                                       int* __restrict__ idxT) {
    __shared__ float rows[8][D_];
    __shared__ float z2s[8];
    __shared__ float d2s[256];
    __shared__ int   idxs[256];
    __shared__ int   bestIdx[8];
    int tid = threadIdx.x;
    size_t row0 = (size_t)blockIdx.x * 8;

    for (int p = 0; p < 8; ++p) {
        float4 v = *reinterpret_cast<const float4*>(Z + (row0 + p) * D_ + tid * 4);
        *reinterpret_cast<float4*>(&rows[p][tid * 4]) = v;
    }
    __syncthreads();

    if (tid < 8) z2s[tid] = np_pairwise_sq_1024(rows[tid]);

    float g2[8];
    #pragma unroll
    for (int r = 0; r < 8; ++r) g2[r] = 0.0f;
    const float* crow = cb + (size_t)tid * D_;
    for (int e = 0; e < D_; e += 4) {
        float4 cv = *reinterpret_cast<const float4*>(crow + e);
        #pragma unroll
        for (int r = 0; r < 8; ++r) {
            g2[r] = __fmaf_rn(__fmul_rn(2.0f, rows[r][e]),     cv.x, g2[r]);
            g2[r] = __fmaf_rn(__fmul_rn(2.0f, rows[r][e + 1]), cv.y, g2[r]);
            g2[r] = __fmaf_rn(__fmul_rn(2.0f, rows[r][e + 2]), cv.z, g2[r]);
            g2[r] = __fmaf_rn(__fmul_rn(2.0f, rows[r][e + 3]), cv.w, g2[r]);
        }
    }
    __syncthreads();

    for (int r = 0; r < 8; ++r) {
        d2s[tid] = __fadd_rn(__fsub_rn(z2s[r], g2[r]), c2[tid]);
        idxs[tid] = tid;
        __syncthreads();
        for (int s = 128; s > 0; s >>= 1) {
            if (tid < s) {
                float ov = d2s[tid + s]; int oi = idxs[tid + s];
                if (ov < d2s[tid] || (ov == d2s[tid] && oi < idxs[tid])) {
                    d2s[tid] = ov; idxs[tid] = oi;
                }
            }
            __syncthreads();
        }
        if (tid == 0) bestIdx[r] = idxs[0];
        __syncthreads();
    }

    if (tid < 8) {
        int row = (int)row0 + tid;
        idxout[row] = (float)bestIdx[tid];
        idxT[((row & 511) << 6) + (row >> 9)] = bestIdx[tid];   // [t][b]
    }
    for (int r = 0; r < 8; ++r) {
        int bi = bestIdx[r];
        float4 v = *reinterpret_cast<const float4*>(cb + (size_t)bi * D_ + tid * 4);
        *reinterpret_cast<float4*>(qout + (row0 + r) * D_ + tid * 4) = v;
    }
}

// ---------------- Gp = bf16-packed (cb @ Wih^T + bih + bhh_{r,z}), [code][j][4] ----------------
__global__ __launch_bounds__(256) void gmat_kernel(const float* __restrict__ cb,
                                                   const float* __restrict__ Wih,
                                                   const float* __restrict__ bih,
                                                   const float* __restrict__ bhh,
                                                   ushort* __restrict__ Gp) {
    int m0 = blockIdx.x * 64;
    int n0 = blockIdx.y * 64;
    __shared__ ushort As[64][136];
    __shared__ ushort Bs[64][136];
    int tid = threadIdx.x;
    int w = tid >> 6, l = tid & 63, lr = l & 15, lk = l >> 4;
    f32x4 acc[4];
    #pragma unroll
    for (int i = 0; i < 4; ++i) acc[i] = f32x4{0.f, 0.f, 0.f, 0.f};

    for (int kc = 0; kc < D_; kc += 128) {
        for (int v = tid; v < 2048; v += 256) {
            int r = (v >> 4) & 63, kp = (v & 15) << 3;
            const float* src = (v < 1024) ? (cb  + (size_t)(m0 + r) * D_ + kc + kp)
                                          : (Wih + (size_t)(n0 + r) * D_ + kc + kp);
            float4 f0 = *reinterpret_cast<const float4*>(src);
            float4 f1 = *reinterpret_cast<const float4*>(src + 4);
            uint4 pk;
            pk.x = (uint)f2bf(f0.x) | ((uint)f2bf(f0.y) << 16);
            pk.y = (uint)f2bf(f0.z) | ((uint)f2bf(f0.w) << 16);
            pk.z = (uint)f2bf(f1.x) | ((uint)f2bf(f1.y) << 16);
            pk.w = (uint)f2bf(f1.z) | ((uint)f2bf(f1.w) << 16);
            ushort* dst = (v < 1024) ? &As[r][kp] : &Bs[r][kp];
            *reinterpret_cast<uint4*>(dst) = pk;
        }
        __syncthreads();
        #pragma unroll
        for (int kk = 0; kk < 4; ++kk) {
            bf16x8 bb = *reinterpret_cast<const bf16x8*>(&Bs[(w << 4) + lr][(kk << 5) + (lk << 3)]);
            #pragma unroll
            for (int mi = 0; mi < 4; ++mi) {
                bf16x8 a = *reinterpret_cast<const bf16x8*>(&As[(mi << 4) + lr][(kk << 5) + (lk << 3)]);
                acc[mi] = __builtin_amdgcn_mfma_f32_16x16x32_bf16(a, bb, acc[mi], 0, 0, 0);
            }
        }
        __syncthreads();
    }
    int n = n0 + (w << 4) + lr;           // 0..3071
    int gate = n >> 10, jj = n & 1023;
    float bias = bih[n] + (gate < 2 ? bhh[n] : 0.0f);
    #pragma unroll
    for (int mi = 0; mi < 4; ++mi)
        #pragma unroll
        for (int reg = 0; reg < 4; ++reg) {
            int m = m0 + (mi << 4) + (lk << 2) + reg;
            Gp[((((size_t)m << 10) | jj) << 2) + gate] = f2bf(acc[mi][reg] + bias);
        }
}

// ---------------- persistent recurrence + inline proj/CPC, custom barrier ----------------
__global__ __launch_bounds__(256, 1) void recur_kernel(
    const ushort* __restrict__ Whh_bf,
    const ushort* __restrict__ Gp,
    const int*    __restrict__ idxT,
    const float*  __restrict__ bhh,
    const ushort* __restrict__ projW_bf,
    const float*  __restrict__ projb,
    const float*  __restrict__ Z,
    ushort* hbuf,     // 2 x 64*1024
    ushort* ring,     // RING x 64*1024
    ushort* hproj,    // RING x 64*1024
    double* accum,
    uint*   bar,
    int RING_)
{
    __shared__ ushort HsS[2][64][136];
    __shared__ ushort WsS[2][48][136];
    __shared__ double red[256];

    const int tid = threadIdx.x;
    const int blk = blockIdx.x;           // 0..63
    const int w = tid >> 6, l = tid & 63;
    const int lr = l & 15, lk = l >> 4;
    const int j0 = blk << 4;
    const int j  = j0 + lr;
    const int b_base = (w << 4) + (lk << 2);
    const float bhhn = bhh[2048 + j];
    float hfp[4] = {0.f, 0.f, 0.f, 0.f};
    uint tgt = 0;

    for (int t = 0; t < T_; ++t) {
        const uint* hin_u = (const uint*)(hbuf + (size_t)(t & 1) * 65536);
        ushort* hout = hbuf + (size_t)((t + 1) & 1) * 65536;
        const int slot = t & (RING_ - 1);

        f32x4 acc[3];
        acc[0] = f32x4{0.f,0.f,0.f,0.f};
        acc[1] = f32x4{0.f,0.f,0.f,0.f};
        acc[2] = f32x4{0.f,0.f,0.f,0.f};

        uint  pfu[16];
        uint4 pfw[3];

        auto issue = [&](int kcb) {
            const int kcu = kcb << 6;      // uint offset within 512-uint row
            const int kcs = kcb << 7;      // ushort offset within 1024-ushort row
            #pragma unroll
            for (int i = 0; i < 4; ++i) {
                int v = tid + (i << 8);                     // 0..1023: h rows
                const uint* src = hin_u + ((v >> 4) << 9) + ((v & 15) << 2) + kcu;
                pfu[4*i+0] = aload(src + 0);
                pfu[4*i+1] = aload(src + 1);
                pfu[4*i+2] = aload(src + 2);
                pfu[4*i+3] = aload(src + 3);
            }
            #pragma unroll
            for (int i = 0; i < 3; ++i) {
                int v = tid + (i << 8);                     // 0..767: W rows (cached)
                int r = v >> 4, kp = (v & 15) << 3;
                int grow = ((r >> 4) << 10) + j0 + (r & 15);
                pfw[i] = *reinterpret_cast<const uint4*>(Whh_bf + ((size_t)grow << 10) + kcs + kp);
            }
        };
        auto commit = [&](int buf) {
            #pragma unroll
            for (int i = 0; i < 4; ++i) {
                int v = tid + (i << 8);
                uint* d = (uint*)&HsS[buf][v >> 4][(v & 15) << 3];
                d[0] = pfu[4*i+0]; d[1] = pfu[4*i+1]; d[2] = pfu[4*i+2]; d[3] = pfu[4*i+3];
            }
            #pragma unroll
            for (int i = 0; i < 3; ++i) {
                int v = tid + (i << 8);
                int r = v >> 4, kp = (v & 15) << 3;
                *reinterpret_cast<uint4*>(&WsS[buf][r][kp]) = pfw[i];
            }
        };

        issue(0);
        commit(0);
        for (int kcb = 0; kcb < 8; ++kcb) {
            if (kcb < 7) issue(kcb + 1);
            __syncthreads();
            const int bq = kcb & 1;
            #pragma unroll
            for (int kk = 0; kk < 4; ++kk) {
                bf16x8 a = *reinterpret_cast<const bf16x8*>(&HsS[bq][(w << 4) + lr][(kk << 5) + (lk << 3)]);
                #pragma unroll
                for (int g = 0; g < 3; ++g) {
                    bf16x8 bb = *reinterpret_cast<const bf16x8*>(&WsS[bq][(g << 4) + lr][(kk << 5) + (lk << 3)]);
                    acc[g] = __builtin_amdgcn_mfma_f32_16x16x32_bf16(a, bb, acc[g], 0, 0, 0);
                }
            }
            if (kcb < 7) commit((kcb + 1) & 1);
        }

        // gates + h update (h carried in registers); Gp has biases folded
        const uint4 it4 = *reinterpret_cast<const uint4*>(idxT + (t << 6) + b_base);
        const int* itp = (const int*)&it4;
        #pragma unroll
        for (int reg = 0; reg < 4; ++reg) {
            const int b = b_base + reg;
            const int ci = itp[reg];
            const ushort4 g4 = *reinterpret_cast<const ushort4*>(Gp + ((((size_t)ci << 10) | j) << 2));
            const float rr = 1.0f / (1.0f + expf(-(bf2f(g4.x) + acc[0][reg])));
            const float zz = 1.0f / (1.0f + expf(-(bf2f(g4.y) + acc[1][reg])));
            const float nn = tanhf(bf2f(g4.z) + rr * (acc[2][reg] + bhhn));
            const float hn = (1.0f - zz) * nn + zz * hfp[reg];
            hfp[reg] = hn;
            const ushort hb = f2bf(hn);
            astore(&hout[(b << 10) + j], hb);
            astore(&ring[((size_t)slot << 16) + (b << 10) + j], hb);
        }
        gbar(bar, tgt);

        if (((t + 1) & (RING_ - 1)) == 0) {
            const int t0 = t + 1 - RING_;
            // ---- proj phase ----
            for (int u = blk; u < (RING_ << 4); u += 64) {
                const int sl = u >> 4;
                const int n0 = (u & 15) << 6;
                const uint* rg_u = (const uint*)(ring + ((size_t)sl << 16));
                f32x4 pacc[4];
                #pragma unroll
                for (int i = 0; i < 4; ++i) pacc[i] = f32x4{0.f,0.f,0.f,0.f};
                for (int kc = 0; kc < D_; kc += 128) {
                    const int kcu = kc >> 1;
                    uint su[16]; uint4 sw[4];
                    #pragma unroll
                    for (int i = 0; i < 4; ++i) {
                        int v = tid + (i << 8);
                        const uint* src = rg_u + ((v >> 4) << 9) + ((v & 15) << 2) + kcu;
                        su[4*i+0] = aload(src + 0); su[4*i+1] = aload(src + 1);
                        su[4*i+2] = aload(src + 2); su[4*i+3] = aload(src + 3);
                    }
                    #pragma unroll
                    for (int i = 0; i < 4; ++i) {
                        int v = tid + (i << 8);
                        int r = v >> 4, kp = (v & 15) << 3;
                        sw[i] = *reinterpret_cast<const uint4*>(projW_bf + (((size_t)(n0 + r)) << 10) + kc + kp);
                    }
                    #pragma unroll
                    for (int i = 0; i < 4; ++i) {
                        int v = tid + (i << 8);
                        int r = v >> 4, kp = (v & 15) << 3;
                        uint* d = (uint*)&HsS[0][r][kp];
                        d[0] = su[4*i+0]; d[1] = su[4*i+1]; d[2] = su[4*i+2]; d[3] = su[4*i+3];
                        *reinterpret_cast<uint4*>(&HsS[1][r][kp]) = sw[i];
                    }
                    __syncthreads();
                    #pragma unroll
                    for (int kk = 0; kk < 4; ++kk) {
                        bf16x8 bb = *reinterpret_cast<const bf16x8*>(&HsS[1][(w << 4) + lr][(kk << 5) + (lk << 3)]);
                        #pragma unroll
                        for (int mi = 0; mi < 4; ++mi) {
                            bf16x8 a = *reinterpret_cast<const bf16x8*>(&HsS[0][(mi << 4) + lr][(kk << 5) + (lk << 3)]);
                            pacc[mi] = __builtin_amdgcn_mfma_f32_16x16x32_bf16(a, bb, pacc[mi], 0, 0, 0);
                        }
                    }
                    __syncthreads();
                }
                const int n = n0 + (w << 4) + lr;
                const float pb = projb[n];
                #pragma unroll
                for (int mi = 0; mi < 4; ++mi)
                    #pragma unroll
                    for (int reg = 0; reg < 4; ++reg) {
                        int b = (mi << 4) + (lk << 2) + reg;
                        astore(&hproj[((size_t)sl << 16) + (b << 10) + n], f2bf(pacc[mi][reg] + pb));
                    }
            }
            gbar(bar, tgt);
            // ---- cpc phase ----
            for (int u = blk; u < RING_ * 3; u += 64) {
                const int sl = u / 3;
                const int kf = u - sl * 3 + 1;
                const int tp = t0 + sl;
                if (tp < T_ - kf) {
                    const uint* hp_u = (const uint*)(hproj + ((size_t)sl << 16));
                    f32x4 pacc[4];
                    #pragma unroll
                    for (int i = 0; i < 4; ++i) pacc[i] = f32x4{0.f,0.f,0.f,0.f};
                    for (int kc = 0; kc < D_; kc += 128) {
                        const int kcu = kc >> 1;
                        uint su[16]; uint4 sw[4];
                        #pragma unroll
                        for (int i = 0; i < 4; ++i) {
                            int v = tid + (i << 8);
                            const uint* src = hp_u + ((v >> 4) << 9) + ((v & 15) << 2) + kcu;
                            su[4*i+0] = aload(src + 0); su[4*i+1] = aload(src + 1);
                            su[4*i+2] = aload(src + 2); su[4*i+3] = aload(src + 3);
                        }
                        #pragma unroll
                        for (int i = 0; i < 4; ++i) {
                            int v = tid + (i << 8);
                            int r = v >> 4, kp = (v & 15) << 3;
                            const float* zsrc = Z + ((((size_t)r << 9) + (tp + kf)) << 10) + kc + kp;
                            float4 f0 = *reinterpret_cast<const float4*>(zsrc);
                            float4 f1 = *reinterpret_cast<const float4*>(zsrc + 4);
                            uint4 pk;
                            pk.x = (uint)f2bf(f0.x) | ((uint)f2bf(f0.y) << 16);
                            pk.y = (uint)f2bf(f0.z) | ((uint)f2bf(f0.w) << 16);
                            pk.z = (uint)f2bf(f1.x) | ((uint)f2bf(f1.y) << 16);
                            pk.w = (uint)f2bf(f1.z) | ((uint)f2bf(f1.w) << 16);
                            sw[i] = pk;
                        }
                        #pragma unroll
                        for (int i = 0; i < 4; ++i) {
                            int v = tid + (i << 8);
                            int r = v >> 4, kp = (v & 15) << 3;
                            uint* d = (uint*)&HsS[0][r][kp];
                            d[0] = su[4*i+0]; d[1] = su[4*i+1]; d[2] = su[4*i+2]; d[3] = su[4*i+3];
                            *reinterpret_cast<uint4*>(&HsS[1][r][kp]) = sw[i];
                        }
                        __syncthreads();
                        #pragma unroll
                        for (int kk = 0; kk < 4; ++kk) {
                            bf16x8 bb = *reinterpret_cast<const bf16x8*>(&HsS[1][(w << 4) + lr][(kk << 5) + (lk << 3)]);
                            #pragma unroll
                            for (int mi = 0; mi < 4; ++mi) {
                                bf16x8 a = *reinterpret_cast<const bf16x8*>(&HsS[0][(mi << 4) + lr][(kk << 5) + (lk << 3)]);
                                pacc[mi] = __builtin_amdgcn_mfma_f32_16x16x32_bf16(a, bb, pacc[mi], 0, 0, 0);
                            }
                        }
                        __syncthreads();
                    }
                    double lsum = 0.0;
                    const int cc = (w << 4) + lr;
                    #pragma unroll
                    for (int mi = 0; mi < 4; ++mi)
                        #pragma unroll
                        for (int reg = 0; reg < 4; ++reg) {
                            int bb2 = (mi << 4) + (lk << 2) + reg;
                            double v = (double)pacc[mi][reg];
                            double s = 1.0 / (1.0 + exp(-v));
                            lsum += (0.1 / 4096.0) * (-log(1.0 - s + 1e-8));
                            if (bb2 == cc) lsum += (1.0 / 64.0) * (-log(s + 1e-8));
                        }
                    red[tid] = lsum; __syncthreads();
                    for (int s2 = 128; s2 > 0; s2 >>= 1) {
                        if (tid < s2) red[tid] += red[tid + s2];
                        __syncthreads();
                    }
                    if (tid == 0) atomicAdd(&accum[0], red[0]);
                }
            }
            gbar(bar, tgt);
        }
    }
}

// ---------------- VQ loss ----------------
__global__ __launch_bounds__(256) void vq_kernel(const float* __restrict__ Z,
                                                 const float* __restrict__ Q,
                                                 double* __restrict__ vq_sum) {
    size_t i0 = ((size_t)blockIdx.x * 256 + threadIdx.x) * 4;
    const size_t stride = (size_t)2048 * 256 * 4;
    double s = 0.0;
    for (size_t i = i0; i < (size_t)NQ_; i += stride) {
        float4 z = *reinterpret_cast<const float4*>(Z + i);
        float4 q = *reinterpret_cast<const float4*>(Q + i);
        double d0 = (double)z.x - (double)q.x;
        double d1 = (double)z.y - (double)q.y;
        double d2 = (double)z.z - (double)q.z;
        double d3 = (double)z.w - (double)q.w;
        s += d0*d0 + d1*d1 + d2*d2 + d3*d3;
    }
    __shared__ double red[256];
    int tid = threadIdx.x;
    red[tid] = s; __syncthreads();
    for (int k = 128; k > 0; k >>= 1) {
        if (tid < k) red[tid] += red[tid + k];
        __syncthreads();
    }
    if (tid == 0) atomicAdd(vq_sum, red[0]);
}

// ---------------- finalize scalars ----------------
__global__ void finalize_kernel(const double* __restrict__ accum,
                                float* __restrict__ scal) {
    double cp = accum[0] / 1527.0;
    double vq = accum[1] * 1.25 / (double)NQ_;
    scal[0] = (float)(cp + vq);
    scal[1] = (float)cp;
    scal[2] = (float)vq;
}

extern "C" void kernel_launch(void* const* d_in, const int* in_sizes, int n_in,
                              void* d_out, int out_size, void* d_ws, size_t ws_size,
                              hipStream_t stream) {
    const float* Z     = (const float*)d_in[0];
    const float* cb    = (const float*)d_in[1];
    const float* Wih   = (const float*)d_in[2];
    const float* Whh   = (const float*)d_in[3];
    const float* bih   = (const float*)d_in[4];
    const float* bhh   = (const float*)d_in[5];
    const float* projW = (const float*)d_in[6];
    const float* projb = (const float*)d_in[7];

    float* out       = (float*)d_out;
    float* quantized = out;
    float* idxout    = out + (size_t)NQ_;
    float* scal      = out + (size_t)NQ_ + NI_;

    char* p = (char*)d_ws;
    ushort* Whh_bf   = (ushort*)p;  p += 6291456;
    ushort* projW_bf = (ushort*)p;  p += 2097152;
    ushort* Gp       = (ushort*)p;  p += 2097152;   // 256*1024*4 bf16
    int*    idxT     = (int*)p;     p += 131072;
    ushort* hbuf     = (ushort*)p;  p += 262144;
    float*  c2f      = (float*)p;   p += 4096;
    char*   ctrl     = p;           p += 4096;
    double* accum = (double*)ctrl;
    uint*   bar   = (uint*)(ctrl + 64);
    size_t fixedsz = (size_t)(p - (char*)d_ws);

    int RINGv = 16;
    if (ws_size >= fixedsz + 2ull * 64 * 131072) RINGv = 64;
    else if (ws_size >= fixedsz + 2ull * 32 * 131072) RINGv = 32;
    ushort* ring  = (ushort*)p;  p += (size_t)RINGv * 131072;
    ushort* hproj = (ushort*)p;

    hipMemsetAsync(hbuf, 0, 262144, stream);
    hipMemsetAsync(ctrl, 0, 4096, stream);

    conv_kernel<<<3072, 256, 0, stream>>>(Whh,   Whh_bf,   3145728);
    conv_kernel<<<1024, 256, 0, stream>>>(projW, projW_bf, 1048576);
    c2_kernel<<<1, 256, 0, stream>>>(cb, c2f);
    quantize_kernel<<<4096, 256, 0, stream>>>(Z, cb, c2f, quantized, idxout, idxT);
    gmat_kernel<<<dim3(4, 48), 256, 0, stream>>>(cb, Wih, bih, bhh, Gp);

    void* kargs[] = { (void*)&Whh_bf, (void*)&Gp, (void*)&idxT, (void*)&bhh,
                      (void*)&projW_bf, (void*)&projb, (void*)&Z,
                      (void*)&hbuf, (void*)&ring, (void*)&hproj,
                      (void*)&accum, (void*)&bar, (void*)&RINGv };
    hipLaunchCooperativeKernel((const void*)recur_kernel, dim3(64), dim3(256),
                               kargs, 0, stream);

    vq_kernel<<<2048, 256, 0, stream>>>(Z, quantized, &accum[1]);
    finalize_kernel<<<1, 1, 0, stream>>>(accum, scal);
}

// Round 7
// 7802.425 us; speedup vs baseline: 2.6046x; 1.6896x over previous
//
#include <hip/hip_runtime.h>
#include <hip/hip_bf16.h>

// Problem dims (fixed)
#define B_ 64
#define T_ 512
#define D_ 1024
#define NQ_ (B_*T_*D_)      // 33554432
#define NI_ (B_*T_)         // 32768

typedef __attribute__((ext_vector_type(8))) short bf16x8;
typedef __attribute__((ext_vector_type(4))) float f32x4;

__device__ inline ushort f2bf(float f) {
    uint x = __float_as_uint(f);
    return (ushort)((x + 0x7FFFu + ((x >> 16) & 1u)) >> 16);
}
__device__ inline float bf2f(ushort u) { return __uint_as_float(((uint)u) << 16); }

__device__ __forceinline__ void astore(ushort* p, ushort v) {
    __hip_atomic_store(p, v, __ATOMIC_RELAXED, __HIP_MEMORY_SCOPE_AGENT);
}

typedef const __attribute__((address_space(1))) void GV;
typedef __attribute__((address_space(3))) void LV;
__device__ __forceinline__ void gll16(const void* g, void* l) {
    __builtin_amdgcn_global_load_lds((GV*)g, (LV*)l, 16, 0, 0);
}

__device__ __forceinline__ float sigf(float x) { return 1.0f / (1.0f + __expf(-x)); }
__device__ __forceinline__ float tanhfast(float x) {
    float e = __expf(-2.0f * fabsf(x));
    float t = (1.0f - e) / (1.0f + e);
    return copysignf(t, x);
}

// ---------------- fp32 -> bf16 conversion ----------------
__global__ __launch_bounds__(256) void conv_kernel(const float* __restrict__ src,
                                                   ushort* __restrict__ dst, int n) {
    int i = (blockIdx.x * 256 + threadIdx.x) * 4;
    if (i >= n) return;
    float4 v = *reinterpret_cast<const float4*>(src + i);
    ushort4 o;
    o.x = f2bf(v.x); o.y = f2bf(v.y); o.z = f2bf(v.z); o.w = f2bf(v.w);
    *reinterpret_cast<ushort4*>(dst + i) = o;
}

// ---------------- Whh -> fragment-order pack: [jb64][g3][c32][lane64][8] ----------------
__global__ __launch_bounds__(256) void whhfr_kernel(const float* __restrict__ Whh,
                                                    ushort* __restrict__ Whh_fr) {
    int l = threadIdx.x & 63;
    int unit = blockIdx.x * 4 + (threadIdx.x >> 6);   // 0..6143 = jb*96 + g*32 + c
    int c = unit & 31;
    int g = (unit >> 5) % 3;
    int jb = unit / 96;
    int row = g * 1024 + jb * 16 + (l & 15);
    int k0 = c * 32 + (l >> 4) * 8;
    const float* s = Whh + (size_t)row * 1024 + k0;
    float4 f0 = *reinterpret_cast<const float4*>(s);
    float4 f1 = *reinterpret_cast<const float4*>(s + 4);
    uint4 pk;
    pk.x = (uint)f2bf(f0.x) | ((uint)f2bf(f0.y) << 16);
    pk.y = (uint)f2bf(f0.z) | ((uint)f2bf(f0.w) << 16);
    pk.z = (uint)f2bf(f1.x) | ((uint)f2bf(f1.y) << 16);
    pk.w = (uint)f2bf(f1.z) | ((uint)f2bf(f1.w) << 16);
    reinterpret_cast<uint4*>(Whh_fr)[(size_t)unit * 64 + l] = pk;
}

// ---- numpy-faithful fp32 pairwise sum of squares, n=1024 ----
__device__ inline float np_pairwise_sq_1024(const float* a) {
    float L[8];
    for (int c = 0; c < 8; ++c) {
        const float* p = a + c * 128;
        float r[8];
        #pragma unroll
        for (int k = 0; k < 8; ++k) r[k] = __fmul_rn(p[k], p[k]);
        for (int i = 8; i < 128; i += 8) {
            #pragma unroll
            for (int k = 0; k < 8; ++k) {
                float v = p[i + k];
                r[k] = __fadd_rn(r[k], __fmul_rn(v, v));
            }
        }
        L[c] = __fadd_rn(__fadd_rn(__fadd_rn(r[0], r[1]), __fadd_rn(r[2], r[3])),
                         __fadd_rn(__fadd_rn(r[4], r[5]), __fadd_rn(r[6], r[7])));
    }
    return __fadd_rn(__fadd_rn(__fadd_rn(L[0], L[1]), __fadd_rn(L[2], L[3])),
                     __fadd_rn(__fadd_rn(L[4], L[5]), __fadd_rn(L[6], L[7])));
}

__global__ __launch_bounds__(256) void c2_kernel(const float* __restrict__ cb,
                                                 float* __restrict__ c2) {
    int j = threadIdx.x;
    c2[j] = np_pairwise_sq_1024(cb + (size_t)j * D_);
}

// ---------------- quantize: fp32-faithful argmin ----------------
__global__ __launch_bounds__(256) void quantize_kernel(const float* __restrict__ Z,
                                                       const float* __restrict__ cb,
                                                       const float* __restrict__ c2,
                                                       float* __restrict__ qout,
                                                       float* __restrict__ idxout,
                                                       int* __restrict__ idxT) {
    __shared__ float rows[8][D_];
    __shared__ float z2s[8];
    __shared__ float d2s[256];
    __shared__ int   idxs[256];
    __shared__ int   bestIdx[8];
    int tid = threadIdx.x;
    size_t row0 = (size_t)blockIdx.x * 8;

    for (int p = 0; p < 8; ++p) {
        float4 v = *reinterpret_cast<const float4*>(Z + (row0 + p) * D_ + tid * 4);
        *reinterpret_cast<float4*>(&rows[p][tid * 4]) = v;
    }
    __syncthreads();

    if (tid < 8) z2s[tid] = np_pairwise_sq_1024(rows[tid]);

    float g2[8];
    #pragma unroll
    for (int r = 0; r < 8; ++r) g2[r] = 0.0f;
    const float* crow = cb + (size_t)tid * D_;
    for (int e = 0; e < D_; e += 4) {
        float4 cv = *reinterpret_cast<const float4*>(crow + e);
        #pragma unroll
        for (int r = 0; r < 8; ++r) {
            g2[r] = __fmaf_rn(__fmul_rn(2.0f, rows[r][e]),     cv.x, g2[r]);
            g2[r] = __fmaf_rn(__fmul_rn(2.0f, rows[r][e + 1]), cv.y, g2[r]);
            g2[r] = __fmaf_rn(__fmul_rn(2.0f, rows[r][e + 2]), cv.z, g2[r]);
            g2[r] = __fmaf_rn(__fmul_rn(2.0f, rows[r][e + 3]), cv.w, g2[r]);
        }
    }
    __syncthreads();

    for (int r = 0; r < 8; ++r) {
        d2s[tid] = __fadd_rn(__fsub_rn(z2s[r], g2[r]), c2[tid]);
        idxs[tid] = tid;
        __syncthreads();
        for (int s = 128; s > 0; s >>= 1) {
            if (tid < s) {
                float ov = d2s[tid + s]; int oi = idxs[tid + s];
                if (ov < d2s[tid] || (ov == d2s[tid] && oi < idxs[tid])) {
                    d2s[tid] = ov; idxs[tid] = oi;
                }
            }
            __syncthreads();
        }
        if (tid == 0) bestIdx[r] = idxs[0];
        __syncthreads();
    }

    if (tid < 8) {
        int row = (int)row0 + tid;
        idxout[row] = (float)bestIdx[tid];
        idxT[((row & 511) << 6) + (row >> 9)] = bestIdx[tid];
    }
    for (int r = 0; r < 8; ++r) {
        int bi = bestIdx[r];
        float4 v = *reinterpret_cast<const float4*>(cb + (size_t)bi * D_ + tid * 4);
        *reinterpret_cast<float4*>(qout + (row0 + r) * D_ + tid * 4) = v;
    }
}

// ---------------- Gp = bf16-packed (cb @ Wih^T + bih + bhh_{r,z}), [code][j][4] ----------------
__global__ __launch_bounds__(256) void gmat_kernel(const float* __restrict__ cb,
                                                   const float* __restrict__ Wih,
                                                   const float* __restrict__ bih,
                                                   const float* __restrict__ bhh,
                                                   ushort* __restrict__ Gp) {
    int m0 = blockIdx.x * 64;
    int n0 = blockIdx.y * 64;
    __shared__ ushort As[64][136];
    __shared__ ushort Bs[64][136];
    int tid = threadIdx.x;
    int w = tid >> 6, l = tid & 63, lr = l & 15, lk = l >> 4;
    f32x4 acc[4];
    #pragma unroll
    for (int i = 0; i < 4; ++i) acc[i] = f32x4{0.f, 0.f, 0.f, 0.f};

    for (int kc = 0; kc < D_; kc += 128) {
        for (int v = tid; v < 2048; v += 256) {
            int r = (v >> 4) & 63, kp = (v & 15) << 3;
            const float* src = (v < 1024) ? (cb  + (size_t)(m0 + r) * D_ + kc + kp)
                                          : (Wih + (size_t)(n0 + r) * D_ + kc + kp);
            float4 f0 = *reinterpret_cast<const float4*>(src);
            float4 f1 = *reinterpret_cast<const float4*>(src + 4);
            uint4 pk;
            pk.x = (uint)f2bf(f0.x) | ((uint)f2bf(f0.y) << 16);
            pk.y = (uint)f2bf(f0.z) | ((uint)f2bf(f0.w) << 16);
            pk.z = (uint)f2bf(f1.x) | ((uint)f2bf(f1.y) << 16);
            pk.w = (uint)f2bf(f1.z) | ((uint)f2bf(f1.w) << 16);
            ushort* dst = (v < 1024) ? &As[r][kp] : &Bs[r][kp];
            *reinterpret_cast<uint4*>(dst) = pk;
        }
        __syncthreads();
        #pragma unroll
        for (int kk = 0; kk < 4; ++kk) {
            bf16x8 bb = *reinterpret_cast<const bf16x8*>(&Bs[(w << 4) + lr][(kk << 5) + (lk << 3)]);
            #pragma unroll
            for (int mi = 0; mi < 4; ++mi) {
                bf16x8 a = *reinterpret_cast<const bf16x8*>(&As[(mi << 4) + lr][(kk << 5) + (lk << 3)]);
                acc[mi] = __builtin_amdgcn_mfma_f32_16x16x32_bf16(a, bb, acc[mi], 0, 0, 0);
            }
        }
        __syncthreads();
    }
    int n = n0 + (w << 4) + lr;
    int gate = n >> 10, jj = n & 1023;
    float bias = bih[n] + (gate < 2 ? bhh[n] : 0.0f);
    #pragma unroll
    for (int mi = 0; mi < 4; ++mi)
        #pragma unroll
        for (int reg = 0; reg < 4; ++reg) {
            int m = m0 + (mi << 4) + (lk << 2) + reg;
            Gp[((((size_t)m << 10) | jj) << 2) + gate] = f2bf(acc[mi][reg] + bias);
        }
}

// ---------------- persistent recurrence (plain launch, 64 blocks = 1/CU) ----------------
__global__ __launch_bounds__(256, 1) void recur_kernel(
    const ushort* __restrict__ Whh_fr,
    const ushort* __restrict__ Gp,
    const int*    __restrict__ idxT,
    const float*  __restrict__ bhh,
    ushort* h_hist,      // [513][64][1024], slot 512 zeroed
    uint*   flags)
{
    extern __shared__ ushort dynlds[];          // [4][32][64][8] = 128 KB
    const int tid = threadIdx.x, blk = blockIdx.x;
    const int w = tid >> 6, l = tid & 63;
    const int lr = l & 15, lk = l >> 4;
    const int j0 = blk << 4, j = j0 + lr;
    const int b_base = (w << 4) + (lk << 2);
    const float bhhn = bhh[2048 + j];
    const ushort* Bbase = Whh_fr + (size_t)blk * 49152;   // 3*32*64*8
    ushort* myfrag = dynlds + (w << 14);                  // w*32*512
    const int rowoff = (((w << 4) + lr) << 10) + (lk << 3);
    float hfp[4] = {0.f, 0.f, 0.f, 0.f};
    bool dead = false;

    for (int t = 0; t < T_; ++t) {
        const ushort* src = h_hist + ((size_t)(t == 0 ? 512 : t - 1) << 16) + rowoff;
        #pragma unroll
        for (int c = 0; c < 32; ++c)
            gll16(src + (c << 5), myfrag + (c << 9));
        __syncthreads();   // drains gll vmcnt

        f32x4 acc0 = {0.f,0.f,0.f,0.f}, acc1 = acc0, acc2 = acc0;
        #pragma unroll 8
        for (int c = 0; c < 32; ++c) {
            bf16x8 a  = *reinterpret_cast<const bf16x8*>(myfrag + (c << 9) + (l << 3));
            bf16x8 b0 = *reinterpret_cast<const bf16x8*>(Bbase +          (c << 9) + (l << 3));
            bf16x8 b1 = *reinterpret_cast<const bf16x8*>(Bbase + 16384 +  (c << 9) + (l << 3));
            bf16x8 b2 = *reinterpret_cast<const bf16x8*>(Bbase + 32768 +  (c << 9) + (l << 3));
            acc0 = __builtin_amdgcn_mfma_f32_16x16x32_bf16(a, b0, acc0, 0, 0, 0);
            acc1 = __builtin_amdgcn_mfma_f32_16x16x32_bf16(a, b1, acc1, 0, 0, 0);
            acc2 = __builtin_amdgcn_mfma_f32_16x16x32_bf16(a, b2, acc2, 0, 0, 0);
        }

        ushort* hw = h_hist + ((size_t)t << 16);
        const uint4 it4 = *reinterpret_cast<const uint4*>(idxT + (t << 6) + b_base);
        const int* itp = (const int*)&it4;
        #pragma unroll
        for (int reg = 0; reg < 4; ++reg) {
            const int b = b_base + reg;
            const ushort4 g4 = *reinterpret_cast<const ushort4*>(Gp + ((((size_t)itp[reg] << 10) | j) << 2));
            float rr = sigf(bf2f(g4.x) + acc0[reg]);
            float zz = sigf(bf2f(g4.y) + acc1[reg]);
            float nn = tanhfast(bf2f(g4.z) + rr * (acc2[reg] + bhhn));
            float hn = (1.0f - zz) * nn + zz * hfp[reg];
            hfp[reg] = hn;
            astore(&hw[(b << 10) + j], f2bf(hn));
        }

        if (t < T_ - 1) {
            __syncthreads();   // drain all waves' h stores (vmcnt0 before barrier)
            if (tid == 0)
                __hip_atomic_store(&flags[blk << 4], (uint)(t + 1),
                                   __ATOMIC_RELEASE, __HIP_MEMORY_SCOPE_AGENT);
            if (tid < 64 && !dead) {
                uint spins = 0;
                while (__hip_atomic_load(&flags[tid << 4], __ATOMIC_RELAXED,
                                         __HIP_MEMORY_SCOPE_AGENT) < (uint)(t + 1)) {
                    __builtin_amdgcn_s_sleep(1);
                    if (++spins > (1u << 23)) { dead = true; break; }  // bounded: no hang
                }
            }
            __syncthreads();
        }
    }
}

// ---------------- proj: hproj[t] = h_hist[t] @ projW^T + projb ----------------
__global__ __launch_bounds__(256) void proj_gemm_kernel(const ushort* __restrict__ h_hist,
                                                        const ushort* __restrict__ projW_bf,
                                                        const float* __restrict__ projb,
                                                        ushort* __restrict__ hproj,
                                                        int ch) {
    int t = ch * 256 + blockIdx.x;
    int n0 = blockIdx.y * 64;
    __shared__ ushort As[64][136];
    __shared__ ushort Bs[64][136];
    int tid = threadIdx.x;
    int w = tid >> 6, l = tid & 63, lr = l & 15, lk = l >> 4;
    f32x4 acc[4];
    #pragma unroll
    for (int i = 0; i < 4; ++i) acc[i] = f32x4{0.f,0.f,0.f,0.f};

    for (int kc = 0; kc < D_; kc += 128) {
        for (int v = tid; v < 2048; v += 256) {
            int r = (v >> 4) & 63, kp = (v & 15) << 3;
            if (v < 1024)
                *reinterpret_cast<uint4*>(&As[r][kp]) =
                    *reinterpret_cast<const uint4*>(h_hist + ((size_t)t << 16) + ((size_t)r << 10) + kc + kp);
            else
                *reinterpret_cast<uint4*>(&Bs[r][kp]) =
                    *reinterpret_cast<const uint4*>(projW_bf + ((size_t)(n0 + r) << 10) + kc + kp);
        }
        __syncthreads();
        #pragma unroll
        for (int kk = 0; kk < 4; ++kk) {
            bf16x8 bb = *reinterpret_cast<const bf16x8*>(&Bs[(w << 4) + lr][(kk << 5) + (lk << 3)]);
            #pragma unroll
            for (int mi = 0; mi < 4; ++mi) {
                bf16x8 a = *reinterpret_cast<const bf16x8*>(&As[(mi << 4) + lr][(kk << 5) + (lk << 3)]);
                acc[mi] = __builtin_amdgcn_mfma_f32_16x16x32_bf16(a, bb, acc[mi], 0, 0, 0);
            }
        }
        __syncthreads();
    }
    int n = n0 + (w << 4) + lr;
    float pb = projb[n];
    #pragma unroll
    for (int mi = 0; mi < 4; ++mi)
        #pragma unroll
        for (int reg = 0; reg < 4; ++reg) {
            int b = (mi << 4) + (lk << 2) + reg;
            hproj[((size_t)(t & 255) << 16) + (b << 10) + n] = f2bf(acc[mi][reg] + pb);
        }
}

// ---------------- CPC loss ----------------
__global__ __launch_bounds__(256) void cpc_loss_kernel(const ushort* __restrict__ hproj,
                                                       const float* __restrict__ Z,
                                                       double* __restrict__ cp_sum,
                                                       int ch) {
    int tp = ch * 256 + blockIdx.x;
    int k = blockIdx.y + 1;
    if (tp >= T_ - k) return;
    __shared__ float Hs[64][33];
    __shared__ float Zs[64][33];
    int tid = threadIdx.x;
    int tx = tid & 15, ty = tid >> 4;
    float acc[4][4] = {};
    const ushort* Hbase = hproj + ((size_t)(tp & 255) << 16);
    const float* Zbase = Z + (size_t)(tp + k) * D_;
    const size_t zstride = (size_t)T_ * D_;
    int r = tid >> 3, c = (tid & 7) << 2;

    for (int kc = 0; kc < D_; kc += 32) {
        #pragma unroll
        for (int p = 0; p < 2; ++p) {
            int rr2 = r + 32 * p;
            ushort4 hv = *reinterpret_cast<const ushort4*>(Hbase + (size_t)rr2 * D_ + kc + c);
            float4 zv = *reinterpret_cast<const float4*>(Zbase + (size_t)rr2 * zstride + kc + c);
            Hs[rr2][c] = bf2f(hv.x); Hs[rr2][c+1] = bf2f(hv.y);
            Hs[rr2][c+2] = bf2f(hv.z); Hs[rr2][c+3] = bf2f(hv.w);
            Zs[rr2][c] = zv.x; Zs[rr2][c+1] = zv.y; Zs[rr2][c+2] = zv.z; Zs[rr2][c+3] = zv.w;
        }
        __syncthreads();
        #pragma unroll
        for (int kk = 0; kk < 32; ++kk) {
            float av[4], bv[4];
            #pragma unroll
            for (int i = 0; i < 4; ++i) av[i] = Hs[ty + 16*i][kk];
            #pragma unroll
            for (int jv = 0; jv < 4; ++jv) bv[jv] = Zs[tx + 16*jv][kk];
            #pragma unroll
            for (int i = 0; i < 4; ++i)
                #pragma unroll
                for (int jv = 0; jv < 4; ++jv)
                    acc[i][jv] = __fmaf_rn(av[i], bv[jv], acc[i][jv]);
        }
        __syncthreads();
    }

    double lsum = 0.0;
    #pragma unroll
    for (int i = 0; i < 4; ++i) {
        #pragma unroll
        for (int jv = 0; jv < 4; ++jv) {
            int bb = ty + 16*i, cc2 = tx + 16*jv;
            double v = (double)acc[i][jv];
            double sg = 1.0 / (1.0 + exp(-v));
            lsum += (0.1 / 4096.0) * (-log(1.0 - sg + 1e-8));
            if (bb == cc2) lsum += (1.0 / 64.0) * (-log(sg + 1e-8));
        }
    }
    __shared__ double red[256];
    red[tid] = lsum; __syncthreads();
    for (int s2 = 128; s2 > 0; s2 >>= 1) {
        if (tid < s2) red[tid] += red[tid + s2];
        __syncthreads();
    }
    if (tid == 0) atomicAdd(cp_sum, red[0]);
}

// ---------------- VQ loss ----------------
__global__ __launch_bounds__(256) void vq_kernel(const float* __restrict__ Z,
                                                 const float* __restrict__ Q,
                                                 double* __restrict__ vq_sum) {
    size_t i0 = ((size_t)blockIdx.x * 256 + threadIdx.x) * 4;
    const size_t stride = (size_t)2048 * 256 * 4;
    double s = 0.0;
    for (size_t i = i0; i < (size_t)NQ_; i += stride) {
        float4 z = *reinterpret_cast<const float4*>(Z + i);
        float4 q = *reinterpret_cast<const float4*>(Q + i);
        double d0 = (double)z.x - (double)q.x;
        double d1 = (double)z.y - (double)q.y;
        double d2 = (double)z.z - (double)q.z;
        double d3 = (double)z.w - (double)q.w;
        s += d0*d0 + d1*d1 + d2*d2 + d3*d3;
    }
    __shared__ double red[256];
    int tid = threadIdx.x;
    red[tid] = s; __syncthreads();
    for (int k = 128; k > 0; k >>= 1) {
        if (tid < k) red[tid] += red[tid + k];
        __syncthreads();
    }
    if (tid == 0) atomicAdd(vq_sum, red[0]);
}

// ---------------- finalize ----------------
__global__ void finalize_kernel(const double* __restrict__ accum,
                                float* __restrict__ scal) {
    double cp = accum[0] / 1527.0;
    double vq = accum[1] * 1.25 / (double)NQ_;
    scal[0] = (float)(cp + vq);
    scal[1] = (float)cp;
    scal[2] = (float)vq;
}

extern "C" void kernel_launch(void* const* d_in, const int* in_sizes, int n_in,
                              void* d_out, int out_size, void* d_ws, size_t ws_size,
                              hipStream_t stream) {
    const float* Z     = (const float*)d_in[0];
    const float* cb    = (const float*)d_in[1];
    const float* Wih   = (const float*)d_in[2];
    const float* Whh   = (const float*)d_in[3];
    const float* bih   = (const float*)d_in[4];
    const float* bhh   = (const float*)d_in[5];
    const float* projW = (const float*)d_in[6];
    const float* projb = (const float*)d_in[7];

    float* out       = (float*)d_out;
    float* quantized = out;
    float* idxout    = out + (size_t)NQ_;
    float* scal      = out + (size_t)NQ_ + NI_;

    char* p = (char*)d_ws;
    ushort* Whh_fr   = (ushort*)p;  p += 6291456;
    ushort* projW_bf = (ushort*)p;  p += 2097152;
    ushort* Gp       = (ushort*)p;  p += 2097152;
    int*    idxT     = (int*)p;     p += 131072;
    float*  c2f      = (float*)p;   p += 4096;
    char*   ctrl     = p;           p += 8192;
    ushort* h_hist   = (ushort*)p;  p += (size_t)513 * 131072;   // 67.24 MB
    ushort* hproj    = (ushort*)p;  p += (size_t)256 * 131072;   // 33.55 MB

    uint*   flags = (uint*)ctrl;
    double* accum = (double*)(ctrl + 4096);

    hipMemsetAsync(ctrl, 0, 8192, stream);
    hipMemsetAsync(h_hist + ((size_t)512 << 16), 0, 131072, stream);  // zero h0 slot

    conv_kernel<<<1024, 256, 0, stream>>>(projW, projW_bf, 1048576);
    whhfr_kernel<<<1536, 256, 0, stream>>>(Whh, Whh_fr);
    c2_kernel<<<1, 256, 0, stream>>>(cb, c2f);
    quantize_kernel<<<4096, 256, 0, stream>>>(Z, cb, c2f, quantized, idxout, idxT);
    gmat_kernel<<<dim3(4, 48), 256, 0, stream>>>(cb, Wih, bih, bhh, Gp);

    // plain launch: 64 blocks, 128 KB dyn LDS -> 1 block/CU, 64 < 256 CUs => co-resident
    hipFuncSetAttribute(reinterpret_cast<const void*>(recur_kernel),
                        hipFuncAttributeMaxDynamicSharedMemorySize, 131072);
    recur_kernel<<<dim3(64), dim3(256), 131072, stream>>>(Whh_fr, Gp, idxT, bhh,
                                                          h_hist, flags);

    for (int ch = 0; ch < 2; ++ch) {
        proj_gemm_kernel<<<dim3(256, 16), 256, 0, stream>>>(h_hist, projW_bf, projb, hproj, ch);
        cpc_loss_kernel<<<dim3(256, 3), 256, 0, stream>>>(hproj, Z, &accum[0], ch);
    }

    vq_kernel<<<2048, 256, 0, stream>>>(Z, quantized, &accum[1]);
    finalize_kernel<<<1, 1, 0, stream>>>(accum, scal);
}

// Round 8
// 5932.317 us; speedup vs baseline: 3.4257x; 1.3152x over previous
//
#include <hip/hip_runtime.h>
#include <hip/hip_bf16.h>

// Problem dims (fixed)
#define B_ 64
#define T_ 512
#define D_ 1024
#define NQ_ (B_*T_*D_)      // 33554432
#define NI_ (B_*T_)         // 32768

typedef __attribute__((ext_vector_type(8))) short bf16x8;
typedef __attribute__((ext_vector_type(4))) float f32x4;

__device__ inline ushort f2bf(float f) {
    uint x = __float_as_uint(f);
    return (ushort)((x + 0x7FFFu + ((x >> 16) & 1u)) >> 16);
}
__device__ inline float bf2f(ushort u) { return __uint_as_float(((uint)u) << 16); }

__device__ __forceinline__ void astore(ushort* p, ushort v) {
    __hip_atomic_store(p, v, __ATOMIC_RELAXED, __HIP_MEMORY_SCOPE_AGENT);
}

typedef const __attribute__((address_space(1))) void GV;
typedef __attribute__((address_space(3))) void LV;
__device__ __forceinline__ void gll16(const void* g, void* l) {
    __builtin_amdgcn_global_load_lds((GV*)g, (LV*)l, 16, 0, 0);
}

__device__ __forceinline__ float sigf(float x) { return 1.0f / (1.0f + __expf(-x)); }
__device__ __forceinline__ float tanhfast(float x) {
    float e = __expf(-2.0f * fabsf(x));
    float t = (1.0f - e) / (1.0f + e);
    return copysignf(t, x);
}

// ---------------- fp32 -> bf16 conversion ----------------
__global__ __launch_bounds__(256) void conv_kernel(const float* __restrict__ src,
                                                   ushort* __restrict__ dst, int n) {
    int i = (blockIdx.x * 256 + threadIdx.x) * 4;
    if (i >= n) return;
    float4 v = *reinterpret_cast<const float4*>(src + i);
    ushort4 o;
    o.x = f2bf(v.x); o.y = f2bf(v.y); o.z = f2bf(v.z); o.w = f2bf(v.w);
    *reinterpret_cast<ushort4*>(dst + i) = o;
}

// ---------------- Whh -> fragment-order pack: [jb64][g3][c32][lane64][8] ----------------
__global__ __launch_bounds__(256) void whhfr_kernel(const float* __restrict__ Whh,
                                                    ushort* __restrict__ Whh_fr) {
    int l = threadIdx.x & 63;
    int unit = blockIdx.x * 4 + (threadIdx.x >> 6);   // 0..6143 = jb*96 + g*32 + c
    int c = unit & 31;
    int g = (unit >> 5) % 3;
    int jb = unit / 96;
    int row = g * 1024 + jb * 16 + (l & 15);
    int k0 = c * 32 + (l >> 4) * 8;
    const float* s = Whh + (size_t)row * 1024 + k0;
    float4 f0 = *reinterpret_cast<const float4*>(s);
    float4 f1 = *reinterpret_cast<const float4*>(s + 4);
    uint4 pk;
    pk.x = (uint)f2bf(f0.x) | ((uint)f2bf(f0.y) << 16);
    pk.y = (uint)f2bf(f0.z) | ((uint)f2bf(f0.w) << 16);
    pk.z = (uint)f2bf(f1.x) | ((uint)f2bf(f1.y) << 16);
    pk.w = (uint)f2bf(f1.z) | ((uint)f2bf(f1.w) << 16);
    reinterpret_cast<uint4*>(Whh_fr)[(size_t)unit * 64 + l] = pk;
}

// ---- numpy-faithful fp32 pairwise sum of squares, n=1024 ----
__device__ inline float np_pairwise_sq_1024(const float* a) {
    float L[8];
    for (int c = 0; c < 8; ++c) {
        const float* p = a + c * 128;
        float r[8];
        #pragma unroll
        for (int k = 0; k < 8; ++k) r[k] = __fmul_rn(p[k], p[k]);
        for (int i = 8; i < 128; i += 8) {
            #pragma unroll
            for (int k = 0; k < 8; ++k) {
                float v = p[i + k];
                r[k] = __fadd_rn(r[k], __fmul_rn(v, v));
            }
        }
        L[c] = __fadd_rn(__fadd_rn(__fadd_rn(r[0], r[1]), __fadd_rn(r[2], r[3])),
                         __fadd_rn(__fadd_rn(r[4], r[5]), __fadd_rn(r[6], r[7])));
    }
    return __fadd_rn(__fadd_rn(__fadd_rn(L[0], L[1]), __fadd_rn(L[2], L[3])),
                     __fadd_rn(__fadd_rn(L[4], L[5]), __fadd_rn(L[6], L[7])));
}

__global__ __launch_bounds__(256) void c2_kernel(const float* __restrict__ cb,
                                                 float* __restrict__ c2) {
    int j = threadIdx.x;
    c2[j] = np_pairwise_sq_1024(cb + (size_t)j * D_);
}

// ---------------- quantize: fp32-faithful argmin ----------------
__global__ __launch_bounds__(256) void quantize_kernel(const float* __restrict__ Z,
                                                       const float* __restrict__ cb,
                                                       const float* __restrict__ c2,
                                                       float* __restrict__ qout,
                                                       float* __restrict__ idxout,
                                                       int* __restrict__ idxT) {
    __shared__ float rows[8][D_];
    __shared__ float z2s[8];
    __shared__ float d2s[256];
    __shared__ int   idxs[256];
    __shared__ int   bestIdx[8];
    int tid = threadIdx.x;
    size_t row0 = (size_t)blockIdx.x * 8;

    for (int p = 0; p < 8; ++p) {
        float4 v = *reinterpret_cast<const float4*>(Z + (row0 + p) * D_ + tid * 4);
        *reinterpret_cast<float4*>(&rows[p][tid * 4]) = v;
    }
    __syncthreads();

    if (tid < 8) z2s[tid] = np_pairwise_sq_1024(rows[tid]);

    float g2[8];
    #pragma unroll
    for (int r = 0; r < 8; ++r) g2[r] = 0.0f;
    const float* crow = cb + (size_t)tid * D_;
    for (int e = 0; e < D_; e += 4) {
        float4 cv = *reinterpret_cast<const float4*>(crow + e);
        #pragma unroll
        for (int r = 0; r < 8; ++r) {
            g2[r] = __fmaf_rn(__fmul_rn(2.0f, rows[r][e]),     cv.x, g2[r]);
            g2[r] = __fmaf_rn(__fmul_rn(2.0f, rows[r][e + 1]), cv.y, g2[r]);
            g2[r] = __fmaf_rn(__fmul_rn(2.0f, rows[r][e + 2]), cv.z, g2[r]);
            g2[r] = __fmaf_rn(__fmul_rn(2.0f, rows[r][e + 3]), cv.w, g2[r]);
        }
    }
    __syncthreads();

    for (int r = 0; r < 8; ++r) {
        d2s[tid] = __fadd_rn(__fsub_rn(z2s[r], g2[r]), c2[tid]);
        idxs[tid] = tid;
        __syncthreads();
        for (int s = 128; s > 0; s >>= 1) {
            if (tid < s) {
                float ov = d2s[tid + s]; int oi = idxs[tid + s];
                if (ov < d2s[tid] || (ov == d2s[tid] && oi < idxs[tid])) {
                    d2s[tid] = ov; idxs[tid] = oi;
                }
            }
            __syncthreads();
        }
        if (tid == 0) bestIdx[r] = idxs[0];
        __syncthreads();
    }

    if (tid < 8) {
        int row = (int)row0 + tid;
        idxout[row] = (float)bestIdx[tid];
        idxT[((row & 511) << 6) + (row >> 9)] = bestIdx[tid];
    }
    for (int r = 0; r < 8; ++r) {
        int bi = bestIdx[r];
        float4 v = *reinterpret_cast<const float4*>(cb + (size_t)bi * D_ + tid * 4);
        *reinterpret_cast<float4*>(qout + (row0 + r) * D_ + tid * 4) = v;
    }
}

// ---------------- Gp = bf16-packed (cb @ Wih^T + bih + bhh_{r,z}), [code][j][4] ----------------
__global__ __launch_bounds__(256) void gmat_kernel(const float* __restrict__ cb,
                                                   const float* __restrict__ Wih,
                                                   const float* __restrict__ bih,
                                                   const float* __restrict__ bhh,
                                                   ushort* __restrict__ Gp) {
    int m0 = blockIdx.x * 64;
    int n0 = blockIdx.y * 64;
    __shared__ ushort As[64][136];
    __shared__ ushort Bs[64][136];
    int tid = threadIdx.x;
    int w = tid >> 6, l = tid & 63, lr = l & 15, lk = l >> 4;
    f32x4 acc[4];
    #pragma unroll
    for (int i = 0; i < 4; ++i) acc[i] = f32x4{0.f, 0.f, 0.f, 0.f};

    for (int kc = 0; kc < D_; kc += 128) {
        for (int v = tid; v < 2048; v += 256) {
            int r = (v >> 4) & 63, kp = (v & 15) << 3;
            const float* src = (v < 1024) ? (cb  + (size_t)(m0 + r) * D_ + kc + kp)
                                          : (Wih + (size_t)(n0 + r) * D_ + kc + kp);
            float4 f0 = *reinterpret_cast<const float4*>(src);
            float4 f1 = *reinterpret_cast<const float4*>(src + 4);
            uint4 pk;
            pk.x = (uint)f2bf(f0.x) | ((uint)f2bf(f0.y) << 16);
            pk.y = (uint)f2bf(f0.z) | ((uint)f2bf(f0.w) << 16);
            pk.z = (uint)f2bf(f1.x) | ((uint)f2bf(f1.y) << 16);
            pk.w = (uint)f2bf(f1.z) | ((uint)f2bf(f1.w) << 16);
            ushort* dst = (v < 1024) ? &As[r][kp] : &Bs[r][kp];
            *reinterpret_cast<uint4*>(dst) = pk;
        }
        __syncthreads();
        #pragma unroll
        for (int kk = 0; kk < 4; ++kk) {
            bf16x8 bb = *reinterpret_cast<const bf16x8*>(&Bs[(w << 4) + lr][(kk << 5) + (lk << 3)]);
            #pragma unroll
            for (int mi = 0; mi < 4; ++mi) {
                bf16x8 a = *reinterpret_cast<const bf16x8*>(&As[(mi << 4) + lr][(kk << 5) + (lk << 3)]);
                acc[mi] = __builtin_amdgcn_mfma_f32_16x16x32_bf16(a, bb, acc[mi], 0, 0, 0);
            }
        }
        __syncthreads();
    }
    int n = n0 + (w << 4) + lr;
    int gate = n >> 10, jj = n & 1023;
    float bias = bih[n] + (gate < 2 ? bhh[n] : 0.0f);
    #pragma unroll
    for (int mi = 0; mi < 4; ++mi)
        #pragma unroll
        for (int reg = 0; reg < 4; ++reg) {
            int m = m0 + (mi << 4) + (lk << 2) + reg;
            Gp[((((size_t)m << 10) | jj) << 2) + gate] = f2bf(acc[mi][reg] + bias);
        }
}

// ---------------- persistent recurrence: Whh held entirely in registers ----------------
__global__ __launch_bounds__(256, 1) void recur_kernel(
    const ushort* __restrict__ Whh_fr,
    const ushort* __restrict__ Gp,
    const int*    __restrict__ idxT,
    const float*  __restrict__ bhh,
    ushort* h_hist,      // [513][64][1024], slot 512 zeroed
    uint*   flags)
{
    extern __shared__ ushort dynlds[];          // [4][32][64][8] = 128 KB
    const int tid = threadIdx.x, blk = blockIdx.x;
    const int w = tid >> 6, l = tid & 63;
    const int lr = l & 15, lk = l >> 4;
    const int j0 = blk << 4, j = j0 + lr;
    const int b_base = (w << 4) + (lk << 2);
    const float bhhn = bhh[2048 + j];
    const ushort* Bbase = Whh_fr + (size_t)blk * 49152;   // 3*32*64*8
    ushort* myfrag = dynlds + (w << 14);                  // w*32*512
    const int rowoff = (((w << 4) + lr) << 10) + (lk << 3);
    float hfp[4] = {0.f, 0.f, 0.f, 0.f};
    bool dead = false;

    // prologue: whole Whh j-slice into registers (96 x bf16x8 = 384 VGPR), static idx
    bf16x8 Bfr[96];
    #pragma unroll
    for (int c = 0; c < 32; ++c) {
        Bfr[c]      = *reinterpret_cast<const bf16x8*>(Bbase +         (c << 9) + (l << 3));
        Bfr[32 + c] = *reinterpret_cast<const bf16x8*>(Bbase + 16384 + (c << 9) + (l << 3));
        Bfr[64 + c] = *reinterpret_cast<const bf16x8*>(Bbase + 32768 + (c << 9) + (l << 3));
    }

    for (int t = 0; t < T_; ++t) {
        const ushort* src = h_hist + ((size_t)(t == 0 ? 512 : t - 1) << 16) + rowoff;
        #pragma unroll
        for (int c = 0; c < 32; ++c)
            gll16(src + (c << 5), myfrag + (c << 9));
        __syncthreads();   // drains gll vmcnt

        f32x4 acc0 = {0.f,0.f,0.f,0.f}, acc1 = acc0, acc2 = acc0;
        #pragma unroll
        for (int c = 0; c < 32; ++c) {
            bf16x8 a = *reinterpret_cast<const bf16x8*>(myfrag + (c << 9) + (l << 3));
            acc0 = __builtin_amdgcn_mfma_f32_16x16x32_bf16(a, Bfr[c],      acc0, 0, 0, 0);
            acc1 = __builtin_amdgcn_mfma_f32_16x16x32_bf16(a, Bfr[32 + c], acc1, 0, 0, 0);
            acc2 = __builtin_amdgcn_mfma_f32_16x16x32_bf16(a, Bfr[64 + c], acc2, 0, 0, 0);
        }

        ushort* hw = h_hist + ((size_t)t << 16);
        const uint4 it4 = *reinterpret_cast<const uint4*>(idxT + (t << 6) + b_base);
        const int* itp = (const int*)&it4;
        #pragma unroll
        for (int reg = 0; reg < 4; ++reg) {
            const int b = b_base + reg;
            const ushort4 g4 = *reinterpret_cast<const ushort4*>(Gp + ((((size_t)itp[reg] << 10) | j) << 2));
            float rr = sigf(bf2f(g4.x) + acc0[reg]);
            float zz = sigf(bf2f(g4.y) + acc1[reg]);
            float nn = tanhfast(bf2f(g4.z) + rr * (acc2[reg] + bhhn));
            float hn = (1.0f - zz) * nn + zz * hfp[reg];
            hfp[reg] = hn;
            astore(&hw[(b << 10) + j], f2bf(hn));
        }

        if (t < T_ - 1) {
            __syncthreads();   // compiler emits vmcnt(0) drain before s_barrier -> h stores landed
            if (tid == 0)
                __hip_atomic_store(&flags[blk << 4], (uint)(t + 1),
                                   __ATOMIC_RELAXED, __HIP_MEMORY_SCOPE_AGENT);
            if (!dead) {       // all 256 threads busy-poll (fast detect + keeps clocks up)
                uint spins = 0;
                while (__hip_atomic_load(&flags[(tid & 63) << 4], __ATOMIC_RELAXED,
                                         __HIP_MEMORY_SCOPE_AGENT) < (uint)(t + 1)) {
                    if (++spins > (1u << 20)) { dead = true; break; }  // bounded: no hang
                }
            }
            __syncthreads();
        }
    }
}

// ---------------- proj: hproj[t] = h_hist[t] @ projW^T + projb ----------------
__global__ __launch_bounds__(256) void proj_gemm_kernel(const ushort* __restrict__ h_hist,
                                                        const ushort* __restrict__ projW_bf,
                                                        const float* __restrict__ projb,
                                                        ushort* __restrict__ hproj,
                                                        int ch) {
    int t = ch * 256 + blockIdx.x;
    int n0 = blockIdx.y * 64;
    __shared__ ushort As[64][136];
    __shared__ ushort Bs[64][136];
    int tid = threadIdx.x;
    int w = tid >> 6, l = tid & 63, lr = l & 15, lk = l >> 4;
    f32x4 acc[4];
    #pragma unroll
    for (int i = 0; i < 4; ++i) acc[i] = f32x4{0.f,0.f,0.f,0.f};

    for (int kc = 0; kc < D_; kc += 128) {
        for (int v = tid; v < 2048; v += 256) {
            int r = (v >> 4) & 63, kp = (v & 15) << 3;
            if (v < 1024)
                *reinterpret_cast<uint4*>(&As[r][kp]) =
                    *reinterpret_cast<const uint4*>(h_hist + ((size_t)t << 16) + ((size_t)r << 10) + kc + kp);
            else
                *reinterpret_cast<uint4*>(&Bs[r][kp]) =
                    *reinterpret_cast<const uint4*>(projW_bf + ((size_t)(n0 + r) << 10) + kc + kp);
        }
        __syncthreads();
        #pragma unroll
        for (int kk = 0; kk < 4; ++kk) {
            bf16x8 bb = *reinterpret_cast<const bf16x8*>(&Bs[(w << 4) + lr][(kk << 5) + (lk << 3)]);
            #pragma unroll
            for (int mi = 0; mi < 4; ++mi) {
                bf16x8 a = *reinterpret_cast<const bf16x8*>(&As[(mi << 4) + lr][(kk << 5) + (lk << 3)]);
                acc[mi] = __builtin_amdgcn_mfma_f32_16x16x32_bf16(a, bb, acc[mi], 0, 0, 0);
            }
        }
        __syncthreads();
    }
    int n = n0 + (w << 4) + lr;
    float pb = projb[n];
    #pragma unroll
    for (int mi = 0; mi < 4; ++mi)
        #pragma unroll
        for (int reg = 0; reg < 4; ++reg) {
            int b = (mi << 4) + (lk << 2) + reg;
            hproj[((size_t)(t & 255) << 16) + (b << 10) + n] = f2bf(acc[mi][reg] + pb);
        }
}

// ---------------- CPC loss ----------------
__global__ __launch_bounds__(256) void cpc_loss_kernel(const ushort* __restrict__ hproj,
                                                       const float* __restrict__ Z,
                                                       double* __restrict__ cp_sum,
                                                       int ch) {
    int tp = ch * 256 + blockIdx.x;
    int k = blockIdx.y + 1;
    if (tp >= T_ - k) return;
    __shared__ float Hs[64][33];
    __shared__ float Zs[64][33];
    int tid = threadIdx.x;
    int tx = tid & 15, ty = tid >> 4;
    float acc[4][4] = {};
    const ushort* Hbase = hproj + ((size_t)(tp & 255) << 16);
    const float* Zbase = Z + (size_t)(tp + k) * D_;
    const size_t zstride = (size_t)T_ * D_;
    int r = tid >> 3, c = (tid & 7) << 2;

    for (int kc = 0; kc < D_; kc += 32) {
        #pragma unroll
        for (int p = 0; p < 2; ++p) {
            int rr2 = r + 32 * p;
            ushort4 hv = *reinterpret_cast<const ushort4*>(Hbase + (size_t)rr2 * D_ + kc + c);
            float4 zv = *reinterpret_cast<const float4*>(Zbase + (size_t)rr2 * zstride + kc + c);
            Hs[rr2][c] = bf2f(hv.x); Hs[rr2][c+1] = bf2f(hv.y);
            Hs[rr2][c+2] = bf2f(hv.z); Hs[rr2][c+3] = bf2f(hv.w);
            Zs[rr2][c] = zv.x; Zs[rr2][c+1] = zv.y; Zs[rr2][c+2] = zv.z; Zs[rr2][c+3] = zv.w;
        }
        __syncthreads();
        #pragma unroll
        for (int kk = 0; kk < 32; ++kk) {
            float av[4], bv[4];
            #pragma unroll
            for (int i = 0; i < 4; ++i) av[i] = Hs[ty + 16*i][kk];
            #pragma unroll
            for (int jv = 0; jv < 4; ++jv) bv[jv] = Zs[tx + 16*jv][kk];
            #pragma unroll
            for (int i = 0; i < 4; ++i)
                #pragma unroll
                for (int jv = 0; jv < 4; ++jv)
                    acc[i][jv] = __fmaf_rn(av[i], bv[jv], acc[i][jv]);
        }
        __syncthreads();
    }

    double lsum = 0.0;
    #pragma unroll
    for (int i = 0; i < 4; ++i) {
        #pragma unroll
        for (int jv = 0; jv < 4; ++jv) {
            int bb = ty + 16*i, cc2 = tx + 16*jv;
            double v = (double)acc[i][jv];
            double sg = 1.0 / (1.0 + exp(-v));
            lsum += (0.1 / 4096.0) * (-log(1.0 - sg + 1e-8));
            if (bb == cc2) lsum += (1.0 / 64.0) * (-log(sg + 1e-8));
        }
    }
    __shared__ double red[256];
    red[tid] = lsum; __syncthreads();
    for (int s2 = 128; s2 > 0; s2 >>= 1) {
        if (tid < s2) red[tid] += red[tid + s2];
        __syncthreads();
    }
    if (tid == 0) atomicAdd(cp_sum, red[0]);
}

// ---------------- VQ loss ----------------
__global__ __launch_bounds__(256) void vq_kernel(const float* __restrict__ Z,
                                                 const float* __restrict__ Q,
                                                 double* __restrict__ vq_sum) {
    size_t i0 = ((size_t)blockIdx.x * 256 + threadIdx.x) * 4;
    const size_t stride = (size_t)2048 * 256 * 4;
    double s = 0.0;
    for (size_t i = i0; i < (size_t)NQ_; i += stride) {
        float4 z = *reinterpret_cast<const float4*>(Z + i);
        float4 q = *reinterpret_cast<const float4*>(Q + i);
        double d0 = (double)z.x - (double)q.x;
        double d1 = (double)z.y - (double)q.y;
        double d2 = (double)z.z - (double)q.z;
        double d3 = (double)z.w - (double)q.w;
        s += d0*d0 + d1*d1 + d2*d2 + d3*d3;
    }
    __shared__ double red[256];
    int tid = threadIdx.x;
    red[tid] = s; __syncthreads();
    for (int k = 128; k > 0; k >>= 1) {
        if (tid < k) red[tid] += red[tid + k];
        __syncthreads();
    }
    if (tid == 0) atomicAdd(vq_sum, red[0]);
}

// ---------------- finalize ----------------
__global__ void finalize_kernel(const double* __restrict__ accum,
                                float* __restrict__ scal) {
    double cp = accum[0] / 1527.0;
    double vq = accum[1] * 1.25 / (double)NQ_;
    scal[0] = (float)(cp + vq);
    scal[1] = (float)cp;
    scal[2] = (float)vq;
}

extern "C" void kernel_launch(void* const* d_in, const int* in_sizes, int n_in,
                              void* d_out, int out_size, void* d_ws, size_t ws_size,
                              hipStream_t stream) {
    const float* Z     = (const float*)d_in[0];
    const float* cb    = (const float*)d_in[1];
    const float* Wih   = (const float*)d_in[2];
    const float* Whh   = (const float*)d_in[3];
    const float* bih   = (const float*)d_in[4];
    const float* bhh   = (const float*)d_in[5];
    const float* projW = (const float*)d_in[6];
    const float* projb = (const float*)d_in[7];

    float* out       = (float*)d_out;
    float* quantized = out;
    float* idxout    = out + (size_t)NQ_;
    float* scal      = out + (size_t)NQ_ + NI_;

    char* p = (char*)d_ws;
    ushort* Whh_fr   = (ushort*)p;  p += 6291456;
    ushort* projW_bf = (ushort*)p;  p += 2097152;
    ushort* Gp       = (ushort*)p;  p += 2097152;
    int*    idxT     = (int*)p;     p += 131072;
    float*  c2f      = (float*)p;   p += 4096;
    char*   ctrl     = p;           p += 8192;
    ushort* h_hist   = (ushort*)p;  p += (size_t)513 * 131072;   // 67.24 MB
    ushort* hproj    = (ushort*)p;  p += (size_t)256 * 131072;   // 33.55 MB

    uint*   flags = (uint*)ctrl;
    double* accum = (double*)(ctrl + 4096);

    hipMemsetAsync(ctrl, 0, 8192, stream);
    hipMemsetAsync(h_hist + ((size_t)512 << 16), 0, 131072, stream);  // zero h0 slot

    conv_kernel<<<1024, 256, 0, stream>>>(projW, projW_bf, 1048576);
    whhfr_kernel<<<1536, 256, 0, stream>>>(Whh, Whh_fr);
    c2_kernel<<<1, 256, 0, stream>>>(cb, c2f);
    quantize_kernel<<<4096, 256, 0, stream>>>(Z, cb, c2f, quantized, idxout, idxT);
    gmat_kernel<<<dim3(4, 48), 256, 0, stream>>>(cb, Wih, bih, bhh, Gp);

    // plain launch: 64 blocks, 128 KB dyn LDS -> 1 block/CU, 64 < 256 CUs => co-resident
    hipFuncSetAttribute(reinterpret_cast<const void*>(recur_kernel),
                        hipFuncAttributeMaxDynamicSharedMemorySize, 131072);
    recur_kernel<<<dim3(64), dim3(256), 131072, stream>>>(Whh_fr, Gp, idxT, bhh,
                                                          h_hist, flags);

    for (int ch = 0; ch < 2; ++ch) {
        proj_gemm_kernel<<<dim3(256, 16), 256, 0, stream>>>(h_hist, projW_bf, projb, hproj, ch);
        cpc_loss_kernel<<<dim3(256, 3), 256, 0, stream>>>(hproj, Z, &accum[0], ch);
    }

    vq_kernel<<<2048, 256, 0, stream>>>(Z, quantized, &accum[1]);
    finalize_kernel<<<1, 1, 0, stream>>>(accum, scal);
}